// Round 6
// baseline (271.824 us; speedup 1.0000x reference)
//
#include <hip/hip_runtime.h>

using short8 = __attribute__((ext_vector_type(8))) short;
using f32x4  = __attribute__((ext_vector_type(4))) float;

__device__ __forceinline__ unsigned short f2b(float f){
  unsigned int u = __float_as_uint(f);
  u = u + 0x7fffu + ((u >> 16) & 1u);   // round-to-nearest-even
  return (unsigned short)(u >> 16);
}
__device__ __forceinline__ float b2f(unsigned short s){
  return __uint_as_float(((unsigned int)s) << 16);
}

// async global->LDS, 16B per lane; lds ptr must be wave-uniform base
__device__ __forceinline__ void gll16(const void* g, void* l){
  __builtin_amdgcn_global_load_lds(
      (const __attribute__((address_space(1))) unsigned int*)g,
      (__attribute__((address_space(3))) unsigned int*)l, 16, 0, 0);
}
__device__ __forceinline__ void vm_wait6(){ asm volatile("s_waitcnt vmcnt(6)" ::: "memory"); }
__device__ __forceinline__ void vm_wait0(){ asm volatile("s_waitcnt vmcnt(0)" ::: "memory"); }

// ------- fused: im2col (0..143) + pool (144..175) + decoder weight transform (176..943) -------
__global__ __launch_bounds__(256) void k_prepwt(const float* __restrict__ w,
    unsigned short* __restrict__ A, float* __restrict__ pooled,
    const float* __restrict__ w1, const float* __restrict__ w2,
    unsigned short* __restrict__ d1, unsigned short* __restrict__ d2){
  int bid = blockIdx.x;
  if(bid >= 176){
    __shared__ float ld[4608];
    int co = bid - 176;    // 768
    const float* src = (co < 512) ? (w1 + (size_t)co * 4608) : (w2 + (size_t)(co - 512) * 4608);
    unsigned short* dst = (co < 512) ? (d1 + (size_t)co * 4608) : (d2 + (size_t)(co - 512) * 4608);
    for(int i = threadIdx.x; i < 4608; i += 256) ld[i] = src[i];
    __syncthreads();
    for(int i = threadIdx.x; i < 4608; i += 256){
      int q = i >> 9, cin = i & 511;
      dst[i] = f2b(ld[cin * 9 + q]);
    }
    return;
  }
  if(bid >= 144){
    int i = (bid - 144) * 256 + threadIdx.x;   // 8192
    const float* p = w + (size_t)i * 9;
    float s = 0.f;
    #pragma unroll
    for(int j = 0; j < 9; j++) s += p[j];
    pooled[i] = s * (1.f / 9.f);
    return;
  }
  int row = bid;           // 144
  int pos = row >> 4, b = row & 15;
  int oh = pos / 3, ow = pos % 3;
  for(int k = threadIdx.x; k < 4608; k += 256){
    int cin = k / 9, q = k - cin * 9;
    int kh = q / 3, kw = q - kh * 3;
    int ih = oh + kh - 1, iw = ow + kw - 1;
    ih = ih < 0 ? -ih : (ih > 2 ? 4 - ih : ih);
    iw = iw < 0 ? -iw : (iw > 2 ? 4 - iw : iw);
    float v = w[((size_t)(b * 512 + cin) * 3 + ih) * 3 + iw];
    A[(size_t)row * 4608 + k] = f2b(v);
  }
}

// ------------- pw[b][4096] and bias[b][512] -------------
__global__ __launch_bounds__(256) void k_pwbias(const float* __restrict__ pooled,
    const float* __restrict__ kp_pw, const float* __restrict__ kp_pb,
    const float* __restrict__ kp_bw, const float* __restrict__ kp_bb,
    float* __restrict__ pw, float* __restrict__ bias){
  int wid = (blockIdx.x * 256 + threadIdx.x) >> 6;   // 4608 waves
  int lane = threadIdx.x & 63;
  const float* row;
  float bv;
  if(wid < 4096){ row = kp_pw + (size_t)wid * 512; bv = kp_pb[wid]; }
  else          { row = kp_bw + (size_t)(wid - 4096) * 512; bv = kp_bb[wid - 4096]; }
  float r[8];
  #pragma unroll
  for(int i = 0; i < 8; i++) r[i] = row[lane + 64 * i];
  for(int b = 0; b < 16; b++){
    float s = 0.f;
    #pragma unroll
    for(int i = 0; i < 8; i++) s += r[i] * pooled[b * 512 + lane + 64 * i];
    #pragma unroll
    for(int o = 32; o >= 1; o >>= 1) s += __shfl_xor(s, o, 64);
    if(lane == 0){
      if(wid < 4096) pw[b * 4096 + wid] = s + bv;
      else           bias[b * 512 + (wid - 4096)] = s + bv;
    }
  }
}

// ------------- KernelPredictor spatial GEMM, 12-way split-K -------------
__global__ __launch_bounds__(256) void k_gemmB(const unsigned short* __restrict__ Aim,
    const float* __restrict__ kp_sw, float* __restrict__ part){
  __shared__ unsigned short Al[144 * 72];
  __shared__ unsigned short Bl[64 * 72];
  int tid = threadIdx.x;
  int lane = tid & 63, wv = tid >> 6;
  int n0 = blockIdx.x * 64;
  int kz = blockIdx.y;
  f32x4 acc[9] = {};
  for(int ks = kz * 6; ks < kz * 6 + 6; ks++){
    int kb = ks * 64;
    for(int c = tid; c < 1152; c += 256){
      int m = c >> 3, kc = c & 7;
      *(int4*)&Al[m * 72 + kc * 8] = *(const int4*)(Aim + (size_t)m * 4608 + kb + kc * 8);
    }
    for(int c = tid; c < 512; c += 256){
      int n = c >> 3, kc = c & 7;
      const float4* src = (const float4*)(kp_sw + (size_t)(n0 + n) * 4608 + kb + kc * 8);
      float4 v0 = src[0], v1 = src[1];
      unsigned short tmp[8];
      tmp[0]=f2b(v0.x); tmp[1]=f2b(v0.y); tmp[2]=f2b(v0.z); tmp[3]=f2b(v0.w);
      tmp[4]=f2b(v1.x); tmp[5]=f2b(v1.y); tmp[6]=f2b(v1.z); tmp[7]=f2b(v1.w);
      *(int4*)&Bl[n * 72 + kc * 8] = *(int4*)tmp;
    }
    __syncthreads();
    int r16 = lane & 15, khalf = lane >> 4;
    #pragma unroll
    for(int kk = 0; kk < 2; kk++){
      int ko = kk * 32 + khalf * 8;
      short8 bf = *(const short8*)&Bl[(wv * 16 + r16) * 72 + ko];
      #pragma unroll
      for(int mf = 0; mf < 9; mf++){
        short8 af = *(const short8*)&Al[(mf * 16 + r16) * 72 + ko];
        acc[mf] = __builtin_amdgcn_mfma_f32_16x16x32_bf16(af, bf, acc[mf], 0, 0, 0);
      }
    }
    __syncthreads();
  }
  int r16 = lane & 15, rgrp = lane >> 4;
  int n = n0 + wv * 16 + r16;
  #pragma unroll
  for(int mf = 0; mf < 9; mf++){
    #pragma unroll
    for(int r = 0; r < 4; r++){
      int m = mf * 16 + rgrp * 4 + r;
      part[((size_t)kz * 144 + m) * 4096 + n] = acc[mf][r];
    }
  }
}

// ------------- split-K reduce + bias + transpose into dw[b][n][9] -------------
__global__ __launch_bounds__(256) void k_red(const float* __restrict__ part,
    const float* __restrict__ kp_sb, float* __restrict__ dw){
  int i = blockIdx.x * 256 + threadIdx.x;   // 589824
  int m = i >> 12, n = i & 4095;
  float s = kp_sb[n];
  #pragma unroll
  for(int kz = 0; kz < 12; kz++) s += part[((size_t)kz * 144 + m) * 4096 + n];
  int q = m >> 4, b = m & 15;
  dw[((size_t)b * 4096 + n) * 9 + q] = s;
}

// ------ AdaConv fused (blocks 0..1023) + y1p pad-ring zero (blocks 1024..1551) ------
// ring must run AFTER k_red (y1p aliases split-K partials) — satisfied by stream order.
__global__ __launch_bounds__(256) void k_ada(const float* __restrict__ x,
    const float* __restrict__ dwb, const float* __restrict__ pwb,
    const float* __restrict__ biasb, unsigned short* __restrict__ y0p,
    unsigned short* __restrict__ y1p){
  int bg = blockIdx.x;
  if(bg >= 1024){
    int i = (bg - 1024) * 256 + threadIdx.x;   // 528*256 = 135168 = 16*132*64
    int b = i / 8448, rem = i - b * 8448;
    int e = rem >> 6, ch8 = rem & 63;
    int hh, ww;
    if(e < 34){ hh = 0; ww = e; }
    else if(e < 68){ hh = 33; ww = e - 34; }
    else if(e < 100){ hh = e - 68 + 1; ww = 0; }
    else { hh = e - 100 + 1; ww = 33; }
    int4 z = {0, 0, 0, 0};
    *(int4*)&y1p[((size_t)(b * 34 + hh) * 34 + ww) * 512 + ch8 * 8] = z;
    return;
  }
  __shared__ float xn[8][1156];
  __shared__ float dwl[576];
  __shared__ float pwl[64];
  __shared__ float bl[8];
  __shared__ float red0[4][8], red1[4][8];
  __shared__ float ms[8], rs[8];
  int b = bg >> 6, g = bg & 63;
  int tid = threadIdx.x;
  int lane = tid & 63, wv = tid >> 6;
  for(int i = tid; i < 576; i += 256) dwl[i] = dwb[((size_t)b * 4096 + g * 64) * 9 + i];
  if(tid < 64) pwl[tid] = pwb[b * 4096 + g * 64 + tid];
  if(tid < 8)  bl[tid]  = biasb[b * 512 + g * 8 + tid];
  // zero y0p pad ring for this (b,g) slice
  if(tid < 132){
    int e = tid, hh, ww;
    if(e < 34){ hh = 0; ww = e; }
    else if(e < 68){ hh = 33; ww = e - 34; }
    else if(e < 100){ hh = e - 68 + 1; ww = 0; }
    else { hh = e - 100 + 1; ww = 33; }
    int4 z = {0, 0, 0, 0};
    *(int4*)&y0p[((size_t)(b * 34 + hh) * 34 + ww) * 512 + g * 8] = z;
  }
  // load interior (float4) + per-channel partial sums
  const float* xb = x + ((size_t)(b * 512 + g * 8)) * 1024;
  int h4 = tid >> 3, w4 = (tid & 7) * 4;
  float s[8], s2[8];
  #pragma unroll
  for(int ci = 0; ci < 8; ci++){
    float4 v = *(const float4*)(xb + ci * 1024 + tid * 4);
    float* dst = &xn[ci][(h4 + 1) * 34 + w4 + 1];
    dst[0] = v.x; dst[1] = v.y; dst[2] = v.z; dst[3] = v.w;
    s[ci]  = v.x + v.y + v.z + v.w;
    s2[ci] = v.x * v.x + v.y * v.y + v.z * v.z + v.w * v.w;
  }
  #pragma unroll
  for(int ci = 0; ci < 8; ci++){
    #pragma unroll
    for(int o = 32; o >= 1; o >>= 1){
      s[ci]  += __shfl_xor(s[ci],  o, 64);
      s2[ci] += __shfl_xor(s2[ci], o, 64);
    }
  }
  if(lane == 0){
    #pragma unroll
    for(int ci = 0; ci < 8; ci++){ red0[wv][ci] = s[ci]; red1[wv][ci] = s2[ci]; }
  }
  __syncthreads();
  if(tid < 8){
    float S  = red0[0][tid] + red0[1][tid] + red0[2][tid] + red0[3][tid];
    float S2 = red1[0][tid] + red1[1][tid] + red1[2][tid] + red1[3][tid];
    float m = S * (1.f / 1024.f);
    ms[tid] = m;
    rs[tid] = rsqrtf(S2 * (1.f / 1024.f) - m * m + 1e-5f);
  }
  __syncthreads();
  // normalize interior in place
  #pragma unroll
  for(int ci = 0; ci < 8; ci++){
    float m = ms[ci], r = rs[ci];
    float* p = &xn[ci][(h4 + 1) * 34 + w4 + 1];
    #pragma unroll
    for(int j = 0; j < 4; j++) p[j] = (p[j] - m) * r;
  }
  __syncthreads();
  // fill reflect halo from normalized interior
  for(int idx = tid; idx < 1056; idx += 256){
    int ci = idx / 132, e = idx - ci * 132;
    int hh, ww;
    if(e < 34){ hh = 0; ww = e; }
    else if(e < 68){ hh = 33; ww = e - 34; }
    else if(e < 100){ hh = e - 68 + 1; ww = 0; }
    else { hh = e - 100 + 1; ww = 33; }
    int h = hh - 1, w2 = ww - 1;
    h  = h  < 0 ? 1 : (h  > 31 ? 30 : h);
    w2 = w2 < 0 ? 1 : (w2 > 31 ? 30 : w2);
    xn[ci][hh * 34 + ww] = xn[ci][(h + 1) * 34 + (w2 + 1)];
  }
  __syncthreads();
  // grouped spatial conv + pointwise + bias
  float acc[4][8] = {};
  #pragma unroll
  for(int i = 0; i < 8; i++){
    #pragma unroll
    for(int q = 0; q < 9; q++){
      int kh = q / 3, kw = q - kh * 3;
      float dvs[8];
      #pragma unroll
      for(int o = 0; o < 8; o++) dvs[o] = dwl[(o * 8 + i) * 9 + q];
      #pragma unroll
      for(int pp = 0; pp < 4; pp++){
        int p = pp * 256 + tid; int h = p >> 5, w = p & 31;
        float v = xn[i][(h + kh) * 34 + (w + kw)];
        #pragma unroll
        for(int o = 0; o < 8; o++) acc[pp][o] += v * dvs[o];
      }
    }
  }
  #pragma unroll
  for(int pp = 0; pp < 4; pp++){
    int p = pp * 256 + tid; int h = p >> 5, w = p & 31;
    unsigned short pack[8];
    #pragma unroll
    for(int o = 0; o < 8; o++){
      float sv = bl[o];
      #pragma unroll
      for(int i2 = 0; i2 < 8; i2++) sv += pwl[o * 8 + i2] * acc[pp][i2];
      pack[o] = f2b(sv);
    }
    *(int4*)&y0p[((size_t)(b * 34 + h + 1) * 34 + (w + 1)) * 512 + g * 8] = *(int4*)pack;
  }
}

// ------------- decoder 3x3 conv: implicit GEMM, BM=256 x BN=128, per-wave 64x64 -------------
// 512 threads = 8 waves (4M x 2N). LDS: A 2x[256][64] + B 2x[128][64] bf16 = 96 KB (1 block/CU).
// T2 swizzle via pre-swizzled source + swizzled ds_read (involution col ^= row&7).
// Counted-vmcnt two-barrier schedule: COMPUTE(buf); barrier; STAGE(t+2->buf); vmcnt(6); barrier.
template<int NCOUT, int OUT_PADDED>
__global__ __launch_bounds__(512) void k_conv(const unsigned short* __restrict__ inp,
    const unsigned short* __restrict__ wt, const float* __restrict__ bias,
    unsigned short* __restrict__ outp){
  __shared__ unsigned short Al[2][256 * 64];
  __shared__ unsigned short Bl[2][128 * 64];
  int tid = threadIdx.x;
  int mt = blockIdx.x;                 // 64 m-tiles of 256 rows
  int n0 = blockIdx.y * 128;
  int b = mt >> 2, h0 = (mt & 3) * 8;
  int lane = tid & 63, wv = tid >> 6;
  int wm = (wv >> 1) * 64, wn = (wv & 1) * 64;
  f32x4 acc[4][4] = {};
  const size_t bbase = (size_t)b * 34 * 34 * 512;

  // staging constants: A chunks c = tid + 512*j (j=0..3), B chunks c = tid + 512*j (j=0..1)
  int kc = tid & 7;
  int mA0 = tid >> 3,           mA1 = (tid + 512) >> 3;
  int mA2 = (tid + 1024) >> 3,  mA3 = (tid + 1536) >> 3;
  int cA0 = kc ^ (mA0 & 7), cA1 = kc ^ (mA1 & 7), cA2 = kc ^ (mA2 & 7), cA3 = kc ^ (mA3 & 7);
  int hA0 = mA0 >> 5, wA0 = mA0 & 31;
  int hA1 = mA1 >> 5, wA1 = mA1 & 31;
  int hA2 = mA2 >> 5, wA2 = mA2 & 31;
  int hA3 = mA3 >> 5, wA3 = mA3 & 31;
  int nB0 = tid >> 3, nB1 = (tid + 512) >> 3;
  int cB0 = kc ^ (nB0 & 7), cB1 = kc ^ (nB1 & 7);
  int ldsO0 = (tid & ~63) * 8;
  int ldsO1 = ldsO0 + 512 * 8;
  int ldsO2 = ldsO0 + 1024 * 8;
  int ldsO3 = ldsO0 + 1536 * 8;
  const unsigned short* aB0 = inp + bbase + cA0 * 8;
  const unsigned short* aB1 = inp + bbase + cA1 * 8;
  const unsigned short* aB2 = inp + bbase + cA2 * 8;
  const unsigned short* aB3 = inp + bbase + cA3 * 8;
  const unsigned short* bB0 = wt + (size_t)(n0 + nB0) * 4608 + cB0 * 8;
  const unsigned short* bB1 = wt + (size_t)(n0 + nB1) * 4608 + cB1 * 8;
  int r16 = lane & 15, khalf = lane >> 4;

#define STAGE(T, BUF) { \
    int q_ = (T) >> 3, cb_ = ((T) & 7) * 64; \
    int kh_ = q_ / 3, kw_ = q_ - kh_ * 3; \
    gll16(aB0 + (size_t)((h0 + hA0 + kh_) * 34 + wA0 + kw_) * 512 + cb_, &Al[BUF][ldsO0]); \
    gll16(aB1 + (size_t)((h0 + hA1 + kh_) * 34 + wA1 + kw_) * 512 + cb_, &Al[BUF][ldsO1]); \
    gll16(aB2 + (size_t)((h0 + hA2 + kh_) * 34 + wA2 + kw_) * 512 + cb_, &Al[BUF][ldsO2]); \
    gll16(aB3 + (size_t)((h0 + hA3 + kh_) * 34 + wA3 + kw_) * 512 + cb_, &Al[BUF][ldsO3]); \
    gll16(bB0 + (size_t)q_ * 512 + cb_, &Bl[BUF][ldsO0]); \
    gll16(bB1 + (size_t)q_ * 512 + cb_, &Bl[BUF][ldsO1]); }

#define CHALF(BUF, SC8) { \
    short8 af[4], bf[4]; \
    _Pragma("unroll") for(int i = 0; i < 4; i++) af[i] = *(const short8*)&Al[BUF][(wm + i * 16 + r16) * 64 + (SC8)]; \
    _Pragma("unroll") for(int i = 0; i < 4; i++) bf[i] = *(const short8*)&Bl[BUF][(wn + i * 16 + r16) * 64 + (SC8)]; \
    __builtin_amdgcn_s_setprio(1); \
    _Pragma("unroll") for(int mi = 0; mi < 4; mi++) \
      _Pragma("unroll") for(int ni = 0; ni < 4; ni++) \
        acc[mi][ni] = __builtin_amdgcn_mfma_f32_16x16x32_bf16(af[mi], bf[ni], acc[mi][ni], 0, 0, 0); \
    __builtin_amdgcn_s_setprio(0); }

#define COMPUTE(BUF) { \
    CHALF(BUF, (khalf ^ (r16 & 7)) * 8) \
    CHALF(BUF, ((4 + khalf) ^ (r16 & 7)) * 8) }

  // prologue: buffers 0,1 in flight; wait for buf0 only (stage(1) stays in flight)
  STAGE(0, 0)
  STAGE(1, 1)
  vm_wait6(); __builtin_amdgcn_s_barrier();
  // main loop: steps 0..69
  for(int t = 0; t < 70; t += 2){
    COMPUTE(0)
    __builtin_amdgcn_s_barrier();
    STAGE(t + 2, 0)
    vm_wait6(); __builtin_amdgcn_s_barrier();
    COMPUTE(1)
    __builtin_amdgcn_s_barrier();
    STAGE(t + 3, 1)
    vm_wait6(); __builtin_amdgcn_s_barrier();
  }
  // tail: steps 70, 71
  COMPUTE(0)
  vm_wait0(); __builtin_amdgcn_s_barrier();
  COMPUTE(1)
#undef STAGE
#undef CHALF
#undef COMPUTE

  int rgrp = lane >> 4;
  #pragma unroll
  for(int ni = 0; ni < 4; ni++){
    int n = n0 + wn + ni * 16 + r16;
    float bv = bias[n];
    #pragma unroll
    for(int mi = 0; mi < 4; mi++){
      #pragma unroll
      for(int r = 0; r < 4; r++){
        int row = wm + mi * 16 + rgrp * 4 + r;
        int h = h0 + (row >> 5), w = row & 31;
        float v = acc[mi][ni][r] + bv;
        v = v > 0.f ? v : 0.f;
        size_t oidx;
        if(OUT_PADDED) oidx = ((size_t)(b * 34 + h + 1) * 34 + (w + 1)) * 512 + n;
        else           oidx = ((size_t)(b * 32 + h) * 32 + w) * NCOUT + n;
        outp[oidx] = f2b(v);
      }
    }
  }
}

// ------------- nearest 2x upsample + NHWC bf16 -> NCHW fp32 -------------
__global__ __launch_bounds__(256) void k_up(const unsigned short* __restrict__ y2,
                                            float* __restrict__ out){
  __shared__ unsigned short ld[32 * 258];
  int bh = blockIdx.x; int b = bh >> 5, h = bh & 31;
  int tid = threadIdx.x;
  const unsigned short* src = y2 + ((size_t)b * 1024 + h * 32) * 256;
  for(int c = tid; c < 1024; c += 256){
    int w = c >> 5, kc = c & 31;
    *(int4*)&ld[w * 258 + kc * 8] = *(const int4*)&src[w * 256 + kc * 8];
  }
  __syncthreads();
  int q = tid & 3, co0 = tid >> 2;
  for(int cc = 0; cc < 4; cc++){
    int co = cc * 64 + co0;
    size_t obase = ((size_t)(b * 256 + co) * 64 + h * 2) * 64 + q * 16;
    #pragma unroll
    for(int i = 0; i < 4; i++){
      float a  = b2f(ld[(q * 8 + i * 2) * 258 + co]);
      float b2 = b2f(ld[(q * 8 + i * 2 + 1) * 258 + co]);
      float4 v = make_float4(a, a, b2, b2);
      *(float4*)&out[obase + i * 4]      = v;
      *(float4*)&out[obase + 64 + i * 4] = v;
    }
  }
}

extern "C" void kernel_launch(void* const* d_in, const int* in_sizes, int n_in,
                              void* d_out, int out_size, void* d_ws, size_t ws_size,
                              hipStream_t stream){
  (void)in_sizes; (void)n_in; (void)out_size; (void)ws_size;
  const float* x      = (const float*)d_in[0];
  const float* w      = (const float*)d_in[1];
  const float* kp_sw  = (const float*)d_in[2];
  const float* kp_sb  = (const float*)d_in[3];
  const float* kp_pw  = (const float*)d_in[4];
  const float* kp_pb  = (const float*)d_in[5];
  const float* kp_bw  = (const float*)d_in[6];
  const float* kp_bb  = (const float*)d_in[7];
  const float* dec_w1 = (const float*)d_in[8];
  const float* dec_b1 = (const float*)d_in[9];
  const float* dec_w2 = (const float*)d_in[10];
  const float* dec_b2 = (const float*)d_in[11];
  char* ws = (char*)d_ws;
  float*          pooled = (float*)(ws);                        // 32 KB
  float*          pw     = (float*)(ws + 32768);                // 256 KB
  float*          bias   = (float*)(ws + 294912);               // 32 KB
  unsigned short* Aim    = (unsigned short*)(ws + 393216);      // 1.33 MB
  float*          dw     = (float*)(ws + 1720320);              // 2.36 MB
  unsigned short* w1t    = (unsigned short*)(ws + 4079616);     // 4.72 MB
  unsigned short* w2t    = (unsigned short*)(ws + 8798208);     // 2.36 MB
  unsigned short* y0p    = (unsigned short*)(ws + 11157504);    // 18.94 MB
  unsigned short* y1p    = (unsigned short*)(ws + 30097408);    // 18.94 MB
  unsigned short* y2     = (unsigned short*)(ws + 49037312);    // 8.39 MB
  // split-K partials (12 x 144 x 4096 fp32 = 28.3 MB) alias y0p + y1p head;
  // consumed by k_red BEFORE k_ada (ring) / k_conv overwrite that region.
  float*          part   = (float*)(ws + 11157504);

  k_prepwt<<<944,  256, 0, stream>>>(w, Aim, pooled, dec_w1, dec_w2, w1t, w2t);
  k_pwbias<<<1152, 256, 0, stream>>>(pooled, kp_pw, kp_pb, kp_bw, kp_bb, pw, bias);
  k_gemmB <<<dim3(64, 12), 256, 0, stream>>>(Aim, kp_sw, part);
  k_red   <<<2304, 256, 0, stream>>>(part, kp_sb, dw);
  k_ada   <<<1552, 256, 0, stream>>>(x, dw, pw, bias, y0p, y1p);
  k_conv<512, 1><<<dim3(64, 4), 512, 0, stream>>>(y0p, w1t, dec_b1, y1p);
  k_conv<256, 0><<<dim3(64, 2), 512, 0, stream>>>(y1p, w2t, dec_b2, y2);
  k_up    <<<512,  256, 0, stream>>>(y2, (float*)d_out);
}

// Round 7
// 249.848 us; speedup vs baseline: 1.0880x; 1.0880x over previous
//
#include <hip/hip_runtime.h>

using short8 = __attribute__((ext_vector_type(8))) short;
using f32x4  = __attribute__((ext_vector_type(4))) float;

__device__ __forceinline__ unsigned short f2b(float f){
  unsigned int u = __float_as_uint(f);
  u = u + 0x7fffu + ((u >> 16) & 1u);   // round-to-nearest-even
  return (unsigned short)(u >> 16);
}
__device__ __forceinline__ float b2f(unsigned short s){
  return __uint_as_float(((unsigned int)s) << 16);
}

// async global->LDS, 16B per lane; lds ptr must be wave-uniform base
__device__ __forceinline__ void gll16(const void* g, void* l){
  __builtin_amdgcn_global_load_lds(
      (const __attribute__((address_space(1))) unsigned int*)g,
      (__attribute__((address_space(3))) unsigned int*)l, 16, 0, 0);
}
__device__ __forceinline__ void vm_wait8(){ asm volatile("s_waitcnt vmcnt(8)" ::: "memory"); }
__device__ __forceinline__ void vm_wait4(){ asm volatile("s_waitcnt vmcnt(4)" ::: "memory"); }
__device__ __forceinline__ void vm_wait0(){ asm volatile("s_waitcnt vmcnt(0)" ::: "memory"); }

// ------- fused: im2col (0..143) + pool (144..175) + decoder weight transform (176..943) -------
__global__ __launch_bounds__(256) void k_prepwt(const float* __restrict__ w,
    unsigned short* __restrict__ A, float* __restrict__ pooled,
    const float* __restrict__ w1, const float* __restrict__ w2,
    unsigned short* __restrict__ d1, unsigned short* __restrict__ d2){
  int bid = blockIdx.x;
  if(bid >= 176){
    __shared__ float ld[4608];
    int co = bid - 176;    // 768
    const float* src = (co < 512) ? (w1 + (size_t)co * 4608) : (w2 + (size_t)(co - 512) * 4608);
    unsigned short* dst = (co < 512) ? (d1 + (size_t)co * 4608) : (d2 + (size_t)(co - 512) * 4608);
    for(int i = threadIdx.x; i < 4608; i += 256) ld[i] = src[i];
    __syncthreads();
    for(int i = threadIdx.x; i < 4608; i += 256){
      int q = i >> 9, cin = i & 511;
      dst[i] = f2b(ld[cin * 9 + q]);
    }
    return;
  }
  if(bid >= 144){
    int i = (bid - 144) * 256 + threadIdx.x;   // 8192
    const float* p = w + (size_t)i * 9;
    float s = 0.f;
    #pragma unroll
    for(int j = 0; j < 9; j++) s += p[j];
    pooled[i] = s * (1.f / 9.f);
    return;
  }
  int row = bid;           // 144
  int pos = row >> 4, b = row & 15;
  int oh = pos / 3, ow = pos % 3;
  for(int k = threadIdx.x; k < 4608; k += 256){
    int cin = k / 9, q = k - cin * 9;
    int kh = q / 3, kw = q - kh * 3;
    int ih = oh + kh - 1, iw = ow + kw - 1;
    ih = ih < 0 ? -ih : (ih > 2 ? 4 - ih : ih);
    iw = iw < 0 ? -iw : (iw > 2 ? 4 - iw : iw);
    float v = w[((size_t)(b * 512 + cin) * 3 + ih) * 3 + iw];
    A[(size_t)row * 4608 + k] = f2b(v);
  }
}

// ------------- pw[b][4096] and bias[b][512] -------------
__global__ __launch_bounds__(256) void k_pwbias(const float* __restrict__ pooled,
    const float* __restrict__ kp_pw, const float* __restrict__ kp_pb,
    const float* __restrict__ kp_bw, const float* __restrict__ kp_bb,
    float* __restrict__ pw, float* __restrict__ bias){
  int wid = (blockIdx.x * 256 + threadIdx.x) >> 6;   // 4608 waves
  int lane = threadIdx.x & 63;
  const float* row;
  float bv;
  if(wid < 4096){ row = kp_pw + (size_t)wid * 512; bv = kp_pb[wid]; }
  else          { row = kp_bw + (size_t)(wid - 4096) * 512; bv = kp_bb[wid - 4096]; }
  float r[8];
  #pragma unroll
  for(int i = 0; i < 8; i++) r[i] = row[lane + 64 * i];
  for(int b = 0; b < 16; b++){
    float s = 0.f;
    #pragma unroll
    for(int i = 0; i < 8; i++) s += r[i] * pooled[b * 512 + lane + 64 * i];
    #pragma unroll
    for(int o = 32; o >= 1; o >>= 1) s += __shfl_xor(s, o, 64);
    if(lane == 0){
      if(wid < 4096) pw[b * 4096 + wid] = s + bv;
      else           bias[b * 512 + (wid - 4096)] = s + bv;
    }
  }
}

// ------------- KernelPredictor spatial GEMM, 12-way split-K -------------
__global__ __launch_bounds__(256) void k_gemmB(const unsigned short* __restrict__ Aim,
    const float* __restrict__ kp_sw, float* __restrict__ part){
  __shared__ unsigned short Al[144 * 72];
  __shared__ unsigned short Bl[64 * 72];
  int tid = threadIdx.x;
  int lane = tid & 63, wv = tid >> 6;
  int n0 = blockIdx.x * 64;
  int kz = blockIdx.y;
  f32x4 acc[9] = {};
  for(int ks = kz * 6; ks < kz * 6 + 6; ks++){
    int kb = ks * 64;
    for(int c = tid; c < 1152; c += 256){
      int m = c >> 3, kc = c & 7;
      *(int4*)&Al[m * 72 + kc * 8] = *(const int4*)(Aim + (size_t)m * 4608 + kb + kc * 8);
    }
    for(int c = tid; c < 512; c += 256){
      int n = c >> 3, kc = c & 7;
      const float4* src = (const float4*)(kp_sw + (size_t)(n0 + n) * 4608 + kb + kc * 8);
      float4 v0 = src[0], v1 = src[1];
      unsigned short tmp[8];
      tmp[0]=f2b(v0.x); tmp[1]=f2b(v0.y); tmp[2]=f2b(v0.z); tmp[3]=f2b(v0.w);
      tmp[4]=f2b(v1.x); tmp[5]=f2b(v1.y); tmp[6]=f2b(v1.z); tmp[7]=f2b(v1.w);
      *(int4*)&Bl[n * 72 + kc * 8] = *(int4*)tmp;
    }
    __syncthreads();
    int r16 = lane & 15, khalf = lane >> 4;
    #pragma unroll
    for(int kk = 0; kk < 2; kk++){
      int ko = kk * 32 + khalf * 8;
      short8 bf = *(const short8*)&Bl[(wv * 16 + r16) * 72 + ko];
      #pragma unroll
      for(int mf = 0; mf < 9; mf++){
        short8 af = *(const short8*)&Al[(mf * 16 + r16) * 72 + ko];
        acc[mf] = __builtin_amdgcn_mfma_f32_16x16x32_bf16(af, bf, acc[mf], 0, 0, 0);
      }
    }
    __syncthreads();
  }
  int r16 = lane & 15, rgrp = lane >> 4;
  int n = n0 + wv * 16 + r16;
  #pragma unroll
  for(int mf = 0; mf < 9; mf++){
    #pragma unroll
    for(int r = 0; r < 4; r++){
      int m = mf * 16 + rgrp * 4 + r;
      part[((size_t)kz * 144 + m) * 4096 + n] = acc[mf][r];
    }
  }
}

// ------------- split-K reduce + bias + transpose into dw[b][n][9] -------------
__global__ __launch_bounds__(256) void k_red(const float* __restrict__ part,
    const float* __restrict__ kp_sb, float* __restrict__ dw){
  int i = blockIdx.x * 256 + threadIdx.x;   // 589824
  int m = i >> 12, n = i & 4095;
  float s = kp_sb[n];
  #pragma unroll
  for(int kz = 0; kz < 12; kz++) s += part[((size_t)kz * 144 + m) * 4096 + n];
  int q = m >> 4, b = m & 15;
  dw[((size_t)b * 4096 + n) * 9 + q] = s;
}

// ------ AdaConv fused (blocks 0..1023) + y1p pad-ring zero (blocks 1024..1551) ------
// ring must run AFTER k_red (y1p aliases split-K partials) — satisfied by stream order.
__global__ __launch_bounds__(256) void k_ada(const float* __restrict__ x,
    const float* __restrict__ dwb, const float* __restrict__ pwb,
    const float* __restrict__ biasb, unsigned short* __restrict__ y0p,
    unsigned short* __restrict__ y1p){
  int bg = blockIdx.x;
  if(bg >= 1024){
    int i = (bg - 1024) * 256 + threadIdx.x;   // 528*256 = 135168 = 16*132*64
    int b = i / 8448, rem = i - b * 8448;
    int e = rem >> 6, ch8 = rem & 63;
    int hh, ww;
    if(e < 34){ hh = 0; ww = e; }
    else if(e < 68){ hh = 33; ww = e - 34; }
    else if(e < 100){ hh = e - 68 + 1; ww = 0; }
    else { hh = e - 100 + 1; ww = 33; }
    int4 z = {0, 0, 0, 0};
    *(int4*)&y1p[((size_t)(b * 34 + hh) * 34 + ww) * 512 + ch8 * 8] = z;
    return;
  }
  __shared__ float xn[8][1156];
  __shared__ float dwl[576];
  __shared__ float pwl[64];
  __shared__ float bl[8];
  __shared__ float red0[4][8], red1[4][8];
  __shared__ float ms[8], rs[8];
  int b = bg >> 6, g = bg & 63;
  int tid = threadIdx.x;
  int lane = tid & 63, wv = tid >> 6;
  for(int i = tid; i < 576; i += 256) dwl[i] = dwb[((size_t)b * 4096 + g * 64) * 9 + i];
  if(tid < 64) pwl[tid] = pwb[b * 4096 + g * 64 + tid];
  if(tid < 8)  bl[tid]  = biasb[b * 512 + g * 8 + tid];
  // zero y0p pad ring for this (b,g) slice
  if(tid < 132){
    int e = tid, hh, ww;
    if(e < 34){ hh = 0; ww = e; }
    else if(e < 68){ hh = 33; ww = e - 34; }
    else if(e < 100){ hh = e - 68 + 1; ww = 0; }
    else { hh = e - 100 + 1; ww = 33; }
    int4 z = {0, 0, 0, 0};
    *(int4*)&y0p[((size_t)(b * 34 + hh) * 34 + ww) * 512 + g * 8] = z;
  }
  // load interior (float4) + per-channel partial sums
  const float* xb = x + ((size_t)(b * 512 + g * 8)) * 1024;
  int h4 = tid >> 3, w4 = (tid & 7) * 4;
  float s[8], s2[8];
  #pragma unroll
  for(int ci = 0; ci < 8; ci++){
    float4 v = *(const float4*)(xb + ci * 1024 + tid * 4);
    float* dst = &xn[ci][(h4 + 1) * 34 + w4 + 1];
    dst[0] = v.x; dst[1] = v.y; dst[2] = v.z; dst[3] = v.w;
    s[ci]  = v.x + v.y + v.z + v.w;
    s2[ci] = v.x * v.x + v.y * v.y + v.z * v.z + v.w * v.w;
  }
  #pragma unroll
  for(int ci = 0; ci < 8; ci++){
    #pragma unroll
    for(int o = 32; o >= 1; o >>= 1){
      s[ci]  += __shfl_xor(s[ci],  o, 64);
      s2[ci] += __shfl_xor(s2[ci], o, 64);
    }
  }
  if(lane == 0){
    #pragma unroll
    for(int ci = 0; ci < 8; ci++){ red0[wv][ci] = s[ci]; red1[wv][ci] = s2[ci]; }
  }
  __syncthreads();
  if(tid < 8){
    float S  = red0[0][tid] + red0[1][tid] + red0[2][tid] + red0[3][tid];
    float S2 = red1[0][tid] + red1[1][tid] + red1[2][tid] + red1[3][tid];
    float m = S * (1.f / 1024.f);
    ms[tid] = m;
    rs[tid] = rsqrtf(S2 * (1.f / 1024.f) - m * m + 1e-5f);
  }
  __syncthreads();
  // normalize interior in place
  #pragma unroll
  for(int ci = 0; ci < 8; ci++){
    float m = ms[ci], r = rs[ci];
    float* p = &xn[ci][(h4 + 1) * 34 + w4 + 1];
    #pragma unroll
    for(int j = 0; j < 4; j++) p[j] = (p[j] - m) * r;
  }
  __syncthreads();
  // fill reflect halo from normalized interior
  for(int idx = tid; idx < 1056; idx += 256){
    int ci = idx / 132, e = idx - ci * 132;
    int hh, ww;
    if(e < 34){ hh = 0; ww = e; }
    else if(e < 68){ hh = 33; ww = e - 34; }
    else if(e < 100){ hh = e - 68 + 1; ww = 0; }
    else { hh = e - 100 + 1; ww = 33; }
    int h = hh - 1, w2 = ww - 1;
    h  = h  < 0 ? 1 : (h  > 31 ? 30 : h);
    w2 = w2 < 0 ? 1 : (w2 > 31 ? 30 : w2);
    xn[ci][hh * 34 + ww] = xn[ci][(h + 1) * 34 + (w2 + 1)];
  }
  __syncthreads();
  // grouped spatial conv + pointwise + bias
  float acc[4][8] = {};
  #pragma unroll
  for(int i = 0; i < 8; i++){
    #pragma unroll
    for(int q = 0; q < 9; q++){
      int kh = q / 3, kw = q - kh * 3;
      float dvs[8];
      #pragma unroll
      for(int o = 0; o < 8; o++) dvs[o] = dwl[(o * 8 + i) * 9 + q];
      #pragma unroll
      for(int pp = 0; pp < 4; pp++){
        int p = pp * 256 + tid; int h = p >> 5, w = p & 31;
        float v = xn[i][(h + kh) * 34 + (w + kw)];
        #pragma unroll
        for(int o = 0; o < 8; o++) acc[pp][o] += v * dvs[o];
      }
    }
  }
  #pragma unroll
  for(int pp = 0; pp < 4; pp++){
    int p = pp * 256 + tid; int h = p >> 5, w = p & 31;
    unsigned short pack[8];
    #pragma unroll
    for(int o = 0; o < 8; o++){
      float sv = bl[o];
      #pragma unroll
      for(int i2 = 0; i2 < 8; i2++) sv += pwl[o * 8 + i2] * acc[pp][i2];
      pack[o] = f2b(sv);
    }
    *(int4*)&y0p[((size_t)(b * 34 + h + 1) * 34 + (w + 1)) * 512 + g * 8] = *(int4*)pack;
  }
}

// ------------- decoder conv v4: BM=128 x BN=128, 4 waves (256 thr), per-wave 64x64 -------------
// LDS 2 x ([128][64] A + [128][64] B) = 64 KB -> 2 blocks/CU. 16 ds_read per 32 MFMA per K-step
// (0.5 reads/MFMA vs 0.75 in the 8-wave version) — attacks the measured LDS-read-BW bound.
// Counted-vmcnt two-barrier schedule (8 loads/stage -> vmcnt(8)); T2 swizzle unchanged.
template<int NCOUT, int OUT_PADDED>
__global__ __launch_bounds__(256) void k_conv4(const unsigned short* __restrict__ inp,
    const unsigned short* __restrict__ wt, const float* __restrict__ bias,
    unsigned short* __restrict__ outp){
  __shared__ unsigned short Al[2][128 * 64];
  __shared__ unsigned short Bl[2][128 * 64];
  int tid = threadIdx.x;
  int mt = blockIdx.x;                 // 128 m-tiles of 128 rows
  int n0 = blockIdx.y * 128;
  int b = mt >> 3, h0 = (mt & 7) * 4;
  int lane = tid & 63, wv = tid >> 6;  // 4 waves: 2M x 2N
  int wm = (wv >> 1) * 64, wn = (wv & 1) * 64;
  f32x4 acc[4][4] = {};
  const size_t bbase = (size_t)b * 34 * 34 * 512;

  // staging: chunks c = tid + 256*j (j=0..3) for each of A and B; row = c>>3, slot = c&7
  int kc = tid & 7;
  int m0 = tid >> 3, m1 = (tid + 256) >> 3, m2 = (tid + 512) >> 3, m3 = (tid + 768) >> 3;
  int cA0 = kc ^ (m0 & 7), cA1 = kc ^ (m1 & 7), cA2 = kc ^ (m2 & 7), cA3 = kc ^ (m3 & 7);
  int hA0 = m0 >> 5, wA0 = m0 & 31;
  int hA1 = m1 >> 5, wA1 = m1 & 31;
  int hA2 = m2 >> 5, wA2 = m2 & 31;
  int hA3 = m3 >> 5, wA3 = m3 & 31;
  int ldsO0 = (tid & ~63) * 8;
  int ldsO1 = ldsO0 + 256 * 8;
  int ldsO2 = ldsO0 + 512 * 8;
  int ldsO3 = ldsO0 + 768 * 8;
  const unsigned short* aB0 = inp + bbase + cA0 * 8;
  const unsigned short* aB1 = inp + bbase + cA1 * 8;
  const unsigned short* aB2 = inp + bbase + cA2 * 8;
  const unsigned short* aB3 = inp + bbase + cA3 * 8;
  const unsigned short* bB0 = wt + (size_t)(n0 + m0) * 4608 + cA0 * 8;
  const unsigned short* bB1 = wt + (size_t)(n0 + m1) * 4608 + cA1 * 8;
  const unsigned short* bB2 = wt + (size_t)(n0 + m2) * 4608 + cA2 * 8;
  const unsigned short* bB3 = wt + (size_t)(n0 + m3) * 4608 + cA3 * 8;
  int r16 = lane & 15, khalf = lane >> 4;

#define STAGE(T, BUF) { \
    int q_ = (T) >> 3, cb_ = ((T) & 7) * 64; \
    int kh_ = q_ / 3, kw_ = q_ - kh_ * 3; \
    gll16(aB0 + (size_t)((h0 + hA0 + kh_) * 34 + wA0 + kw_) * 512 + cb_, &Al[BUF][ldsO0]); \
    gll16(aB1 + (size_t)((h0 + hA1 + kh_) * 34 + wA1 + kw_) * 512 + cb_, &Al[BUF][ldsO1]); \
    gll16(aB2 + (size_t)((h0 + hA2 + kh_) * 34 + wA2 + kw_) * 512 + cb_, &Al[BUF][ldsO2]); \
    gll16(aB3 + (size_t)((h0 + hA3 + kh_) * 34 + wA3 + kw_) * 512 + cb_, &Al[BUF][ldsO3]); \
    gll16(bB0 + (size_t)q_ * 512 + cb_, &Bl[BUF][ldsO0]); \
    gll16(bB1 + (size_t)q_ * 512 + cb_, &Bl[BUF][ldsO1]); \
    gll16(bB2 + (size_t)q_ * 512 + cb_, &Bl[BUF][ldsO2]); \
    gll16(bB3 + (size_t)q_ * 512 + cb_, &Bl[BUF][ldsO3]); }

#define CHALF(BUF, SC8) { \
    short8 af[4], bf[4]; \
    _Pragma("unroll") for(int i = 0; i < 4; i++) af[i] = *(const short8*)&Al[BUF][(wm + i * 16 + r16) * 64 + (SC8)]; \
    _Pragma("unroll") for(int i = 0; i < 4; i++) bf[i] = *(const short8*)&Bl[BUF][(wn + i * 16 + r16) * 64 + (SC8)]; \
    __builtin_amdgcn_s_setprio(1); \
    _Pragma("unroll") for(int mi = 0; mi < 4; mi++) \
      _Pragma("unroll") for(int ni = 0; ni < 4; ni++) \
        acc[mi][ni] = __builtin_amdgcn_mfma_f32_16x16x32_bf16(af[mi], bf[ni], acc[mi][ni], 0, 0, 0); \
    __builtin_amdgcn_s_setprio(0); }

#define COMPUTE(BUF) { \
    CHALF(BUF, (khalf ^ (r16 & 7)) * 8) \
    CHALF(BUF, ((4 + khalf) ^ (r16 & 7)) * 8) }

  STAGE(0, 0)
  STAGE(1, 1)
  vm_wait8(); __builtin_amdgcn_s_barrier();
  for(int t = 0; t < 70; t += 2){
    COMPUTE(0)
    __builtin_amdgcn_s_barrier();
    STAGE(t + 2, 0)
    vm_wait8(); __builtin_amdgcn_s_barrier();
    COMPUTE(1)
    __builtin_amdgcn_s_barrier();
    STAGE(t + 3, 1)
    vm_wait8(); __builtin_amdgcn_s_barrier();
  }
  COMPUTE(0)
  vm_wait0(); __builtin_amdgcn_s_barrier();
  COMPUTE(1)
#undef STAGE
#undef CHALF
#undef COMPUTE

  int rgrp = lane >> 4;
  #pragma unroll
  for(int ni = 0; ni < 4; ni++){
    int n = n0 + wn + ni * 16 + r16;
    float bv = bias[n];
    #pragma unroll
    for(int mi = 0; mi < 4; mi++){
      #pragma unroll
      for(int r = 0; r < 4; r++){
        int row = wm + mi * 16 + rgrp * 4 + r;
        int h = h0 + (row >> 5), w = row & 31;
        float v = acc[mi][ni][r] + bv;
        v = v > 0.f ? v : 0.f;
        size_t oidx;
        if(OUT_PADDED) oidx = ((size_t)(b * 34 + h + 1) * 34 + (w + 1)) * 512 + n;
        else           oidx = ((size_t)(b * 32 + h) * 32 + w) * NCOUT + n;
        outp[oidx] = f2b(v);
      }
    }
  }
}

// ------------- decoder conv v8 (R4-proven): 8 waves, per-wave 64x32 — used for conv2 -------------
template<int NCOUT, int OUT_PADDED>
__global__ __launch_bounds__(512) void k_conv8(const unsigned short* __restrict__ inp,
    const unsigned short* __restrict__ wt, const float* __restrict__ bias,
    unsigned short* __restrict__ outp){
  __shared__ unsigned short Al[2][128 * 64];
  __shared__ unsigned short Bl[2][128 * 64];
  int tid = threadIdx.x;
  int mt = blockIdx.x;
  int n0 = blockIdx.y * 128;
  int b = mt >> 3, h0 = (mt & 7) * 4;
  int lane = tid & 63, wv = tid >> 6;
  int wm = (wv >> 2) * 64, wn = (wv & 3) * 32;
  f32x4 acc[4][2] = {};
  const size_t bbase = (size_t)b * 34 * 34 * 512;

  int kc = tid & 7;
  int m0 = tid >> 3, m1 = (tid + 512) >> 3;
  int colA0 = kc ^ (m0 & 7), colA1 = kc ^ (m1 & 7);
  int mh0 = m0 >> 5, mw0 = m0 & 31;
  int mh1 = m1 >> 5, mw1 = m1 & 31;
  int ldsO0 = (tid & ~63) * 8;
  int ldsO1 = ldsO0 + 512 * 8;
  const unsigned short* a0base = inp + bbase + colA0 * 8;
  const unsigned short* a1base = inp + bbase + colA1 * 8;
  const unsigned short* b0base = wt + (size_t)(n0 + m0) * 4608 + colA0 * 8;
  const unsigned short* b1base = wt + (size_t)(n0 + m1) * 4608 + colA1 * 8;
  int r16 = lane & 15, khalf = lane >> 4;

#define STAGE(T, BUF) { \
    int q_ = (T) >> 3, cb_ = ((T) & 7) * 64; \
    int kh_ = q_ / 3, kw_ = q_ - kh_ * 3; \
    gll16(a0base + (size_t)((h0 + mh0 + kh_) * 34 + mw0 + kw_) * 512 + cb_, &Al[BUF][ldsO0]); \
    gll16(a1base + (size_t)((h0 + mh1 + kh_) * 34 + mw1 + kw_) * 512 + cb_, &Al[BUF][ldsO1]); \
    gll16(b0base + (size_t)q_ * 512 + cb_, &Bl[BUF][ldsO0]); \
    gll16(b1base + (size_t)q_ * 512 + cb_, &Bl[BUF][ldsO1]); }

#define COMPUTE(BUF) { \
    const unsigned short* Ab = Al[BUF]; const unsigned short* Bb = Bl[BUF]; \
    { int sc8 = (khalf ^ (r16 & 7)) * 8; \
      short8 af[4], bf[2]; \
      _Pragma("unroll") for(int i = 0; i < 4; i++) af[i] = *(const short8*)&Ab[(wm + i * 16 + r16) * 64 + sc8]; \
      _Pragma("unroll") for(int i = 0; i < 2; i++) bf[i] = *(const short8*)&Bb[(wn + i * 16 + r16) * 64 + sc8]; \
      __builtin_amdgcn_s_setprio(1); \
      _Pragma("unroll") for(int mi = 0; mi < 4; mi++) \
        _Pragma("unroll") for(int ni = 0; ni < 2; ni++) \
          acc[mi][ni] = __builtin_amdgcn_mfma_f32_16x16x32_bf16(af[mi], bf[ni], acc[mi][ni], 0, 0, 0); \
      __builtin_amdgcn_s_setprio(0); } \
    { int sc8 = ((4 + khalf) ^ (r16 & 7)) * 8; \
      short8 af[4], bf[2]; \
      _Pragma("unroll") for(int i = 0; i < 4; i++) af[i] = *(const short8*)&Ab[(wm + i * 16 + r16) * 64 + sc8]; \
      _Pragma("unroll") for(int i = 0; i < 2; i++) bf[i] = *(const short8*)&Bb[(wn + i * 16 + r16) * 64 + sc8]; \
      __builtin_amdgcn_s_setprio(1); \
      _Pragma("unroll") for(int mi = 0; mi < 4; mi++) \
        _Pragma("unroll") for(int ni = 0; ni < 2; ni++) \
          acc[mi][ni] = __builtin_amdgcn_mfma_f32_16x16x32_bf16(af[mi], bf[ni], acc[mi][ni], 0, 0, 0); \
      __builtin_amdgcn_s_setprio(0); } }

  STAGE(0, 0)
  STAGE(1, 1)
  vm_wait4(); __builtin_amdgcn_s_barrier();
  for(int t = 0; t < 70; t += 2){
    COMPUTE(0)
    __builtin_amdgcn_s_barrier();
    STAGE(t + 2, 0)
    vm_wait4(); __builtin_amdgcn_s_barrier();
    COMPUTE(1)
    __builtin_amdgcn_s_barrier();
    STAGE(t + 3, 1)
    vm_wait4(); __builtin_amdgcn_s_barrier();
  }
  COMPUTE(0)
  vm_wait0(); __builtin_amdgcn_s_barrier();
  COMPUTE(1)
#undef STAGE
#undef COMPUTE

  int rgrp = lane >> 4;
  #pragma unroll
  for(int ni = 0; ni < 2; ni++){
    int n = n0 + wn + ni * 16 + r16;
    float bv = bias[n];
    #pragma unroll
    for(int mi = 0; mi < 4; mi++){
      #pragma unroll
      for(int r = 0; r < 4; r++){
        int row = wm + mi * 16 + rgrp * 4 + r;
        int h = h0 + (row >> 5), w = row & 31;
        float v = acc[mi][ni][r] + bv;
        v = v > 0.f ? v : 0.f;
        size_t oidx;
        if(OUT_PADDED) oidx = ((size_t)(b * 34 + h + 1) * 34 + (w + 1)) * 512 + n;
        else           oidx = ((size_t)(b * 32 + h) * 32 + w) * NCOUT + n;
        outp[oidx] = f2b(v);
      }
    }
  }
}

// ------------- nearest 2x upsample + NHWC bf16 -> NCHW fp32 -------------
__global__ __launch_bounds__(256) void k_up(const unsigned short* __restrict__ y2,
                                            float* __restrict__ out){
  __shared__ unsigned short ld[32 * 258];
  int bh = blockIdx.x; int b = bh >> 5, h = bh & 31;
  int tid = threadIdx.x;
  const unsigned short* src = y2 + ((size_t)b * 1024 + h * 32) * 256;
  for(int c = tid; c < 1024; c += 256){
    int w = c >> 5, kc = c & 31;
    *(int4*)&ld[w * 258 + kc * 8] = *(const int4*)&src[w * 256 + kc * 8];
  }
  __syncthreads();
  int q = tid & 3, co0 = tid >> 2;
  for(int cc = 0; cc < 4; cc++){
    int co = cc * 64 + co0;
    size_t obase = ((size_t)(b * 256 + co) * 64 + h * 2) * 64 + q * 16;
    #pragma unroll
    for(int i = 0; i < 4; i++){
      float a  = b2f(ld[(q * 8 + i * 2) * 258 + co]);
      float b2 = b2f(ld[(q * 8 + i * 2 + 1) * 258 + co]);
      float4 v = make_float4(a, a, b2, b2);
      *(float4*)&out[obase + i * 4]      = v;
      *(float4*)&out[obase + 64 + i * 4] = v;
    }
  }
}

extern "C" void kernel_launch(void* const* d_in, const int* in_sizes, int n_in,
                              void* d_out, int out_size, void* d_ws, size_t ws_size,
                              hipStream_t stream){
  (void)in_sizes; (void)n_in; (void)out_size; (void)ws_size;
  const float* x      = (const float*)d_in[0];
  const float* w      = (const float*)d_in[1];
  const float* kp_sw  = (const float*)d_in[2];
  const float* kp_sb  = (const float*)d_in[3];
  const float* kp_pw  = (const float*)d_in[4];
  const float* kp_pb  = (const float*)d_in[5];
  const float* kp_bw  = (const float*)d_in[6];
  const float* kp_bb  = (const float*)d_in[7];
  const float* dec_w1 = (const float*)d_in[8];
  const float* dec_b1 = (const float*)d_in[9];
  const float* dec_w2 = (const float*)d_in[10];
  const float* dec_b2 = (const float*)d_in[11];
  char* ws = (char*)d_ws;
  float*          pooled = (float*)(ws);                        // 32 KB
  float*          pw     = (float*)(ws + 32768);                // 256 KB
  float*          bias   = (float*)(ws + 294912);               // 32 KB
  unsigned short* Aim    = (unsigned short*)(ws + 393216);      // 1.33 MB
  float*          dw     = (float*)(ws + 1720320);              // 2.36 MB
  unsigned short* w1t    = (unsigned short*)(ws + 4079616);     // 4.72 MB
  unsigned short* w2t    = (unsigned short*)(ws + 8798208);     // 2.36 MB
  unsigned short* y0p    = (unsigned short*)(ws + 11157504);    // 18.94 MB
  unsigned short* y1p    = (unsigned short*)(ws + 30097408);    // 18.94 MB
  unsigned short* y2     = (unsigned short*)(ws + 49037312);    // 8.39 MB
  // split-K partials (12 x 144 x 4096 fp32 = 28.3 MB) alias y0p + y1p head;
  // consumed by k_red BEFORE k_ada (ring) / k_conv overwrite that region.
  float*          part   = (float*)(ws + 11157504);

  k_prepwt<<<944,  256, 0, stream>>>(w, Aim, pooled, dec_w1, dec_w2, w1t, w2t);
  k_pwbias<<<1152, 256, 0, stream>>>(pooled, kp_pw, kp_pb, kp_bw, kp_bb, pw, bias);
  k_gemmB <<<dim3(64, 12), 256, 0, stream>>>(Aim, kp_sw, part);
  k_red   <<<2304, 256, 0, stream>>>(part, kp_sb, dw);
  k_ada   <<<1552, 256, 0, stream>>>(x, dw, pw, bias, y0p, y1p);
  k_conv4<512, 1><<<dim3(128, 4), 256, 0, stream>>>(y0p, w1t, dec_b1, y1p);
  k_conv8<256, 0><<<dim3(128, 2), 512, 0, stream>>>(y1p, w2t, dec_b2, y2);
  k_up    <<<512,  256, 0, stream>>>(y2, (float*)d_out);
}

// Round 8
// 219.438 us; speedup vs baseline: 1.2387x; 1.1386x over previous
//
#include <hip/hip_runtime.h>

using short8 = __attribute__((ext_vector_type(8))) short;
using f32x4  = __attribute__((ext_vector_type(4))) float;

__device__ __forceinline__ unsigned short f2b(float f){
  unsigned int u = __float_as_uint(f);
  u = u + 0x7fffu + ((u >> 16) & 1u);   // round-to-nearest-even
  return (unsigned short)(u >> 16);
}
__device__ __forceinline__ float b2f(unsigned short s){
  return __uint_as_float(((unsigned int)s) << 16);
}

// async global->LDS, 16B per lane; lds ptr must be wave-uniform base
__device__ __forceinline__ void gll16(const void* g, void* l){
  __builtin_amdgcn_global_load_lds(
      (const __attribute__((address_space(1))) unsigned int*)g,
      (__attribute__((address_space(3))) unsigned int*)l, 16, 0, 0);
}
__device__ __forceinline__ void vm_wait4(){ asm volatile("s_waitcnt vmcnt(4)" ::: "memory"); }
__device__ __forceinline__ void vm_wait0(){ asm volatile("s_waitcnt vmcnt(0)" ::: "memory"); }

// ------- fused: im2col (0..143) + pool (144..175) + decoder weight transform (176..943) -------
__global__ __launch_bounds__(256) void k_prepwt(const float* __restrict__ w,
    unsigned short* __restrict__ A, float* __restrict__ pooled,
    const float* __restrict__ w1, const float* __restrict__ w2,
    unsigned short* __restrict__ d1, unsigned short* __restrict__ d2){
  int bid = blockIdx.x;
  if(bid >= 176){
    __shared__ float ld[4608];
    int co = bid - 176;    // 768
    const float* src = (co < 512) ? (w1 + (size_t)co * 4608) : (w2 + (size_t)(co - 512) * 4608);
    unsigned short* dst = (co < 512) ? (d1 + (size_t)co * 4608) : (d2 + (size_t)(co - 512) * 4608);
    for(int i = threadIdx.x; i < 4608; i += 256) ld[i] = src[i];
    __syncthreads();
    for(int i = threadIdx.x; i < 4608; i += 256){
      int q = i >> 9, cin = i & 511;
      dst[i] = f2b(ld[cin * 9 + q]);
    }
    return;
  }
  if(bid >= 144){
    int i = (bid - 144) * 256 + threadIdx.x;   // 8192
    const float* p = w + (size_t)i * 9;
    float s = 0.f;
    #pragma unroll
    for(int j = 0; j < 9; j++) s += p[j];
    pooled[i] = s * (1.f / 9.f);
    return;
  }
  int row = bid;           // 144
  int pos = row >> 4, b = row & 15;
  int oh = pos / 3, ow = pos % 3;
  for(int k = threadIdx.x; k < 4608; k += 256){
    int cin = k / 9, q = k - cin * 9;
    int kh = q / 3, kw = q - kh * 3;
    int ih = oh + kh - 1, iw = ow + kw - 1;
    ih = ih < 0 ? -ih : (ih > 2 ? 4 - ih : ih);
    iw = iw < 0 ? -iw : (iw > 2 ? 4 - iw : iw);
    float v = w[((size_t)(b * 512 + cin) * 3 + ih) * 3 + iw];
    A[(size_t)row * 4608 + k] = f2b(v);
  }
}

// ------- merged: KernelPredictor spatial GEMM 12-way split-K (blocks 0..767) + pw/bias (768..1919) -------
__global__ __launch_bounds__(256) void k_pwgemm(const unsigned short* __restrict__ Aim,
    const float* __restrict__ kp_sw, float* __restrict__ part,
    const float* __restrict__ pooled,
    const float* __restrict__ kp_pw, const float* __restrict__ kp_pb,
    const float* __restrict__ kp_bw, const float* __restrict__ kp_bb,
    float* __restrict__ pw, float* __restrict__ bias){
  __shared__ unsigned short Al[144 * 72];
  __shared__ unsigned short Bl[64 * 72];
  int bid = blockIdx.x;
  int tid = threadIdx.x;
  int lane = tid & 63, wv = tid >> 6;
  if(bid >= 768){
    int wid = ((bid - 768) * 256 + tid) >> 6;   // 4608 waves
    const float* row;
    float bv;
    if(wid < 4096){ row = kp_pw + (size_t)wid * 512; bv = kp_pb[wid]; }
    else          { row = kp_bw + (size_t)(wid - 4096) * 512; bv = kp_bb[wid - 4096]; }
    float r[8];
    #pragma unroll
    for(int i = 0; i < 8; i++) r[i] = row[lane + 64 * i];
    for(int b = 0; b < 16; b++){
      float s = 0.f;
      #pragma unroll
      for(int i = 0; i < 8; i++) s += r[i] * pooled[b * 512 + lane + 64 * i];
      #pragma unroll
      for(int o = 32; o >= 1; o >>= 1) s += __shfl_xor(s, o, 64);
      if(lane == 0){
        if(wid < 4096) pw[b * 4096 + wid] = s + bv;
        else           bias[b * 512 + (wid - 4096)] = s + bv;
      }
    }
    return;
  }
  int n0 = (bid & 63) * 64;
  int kz = bid >> 6;
  f32x4 acc[9] = {};
  for(int ks = kz * 6; ks < kz * 6 + 6; ks++){
    int kb = ks * 64;
    for(int c = tid; c < 1152; c += 256){
      int m = c >> 3, kc = c & 7;
      *(int4*)&Al[m * 72 + kc * 8] = *(const int4*)(Aim + (size_t)m * 4608 + kb + kc * 8);
    }
    for(int c = tid; c < 512; c += 256){
      int n = c >> 3, kc = c & 7;
      const float4* src = (const float4*)(kp_sw + (size_t)(n0 + n) * 4608 + kb + kc * 8);
      float4 v0 = src[0], v1 = src[1];
      unsigned short tmp[8];
      tmp[0]=f2b(v0.x); tmp[1]=f2b(v0.y); tmp[2]=f2b(v0.z); tmp[3]=f2b(v0.w);
      tmp[4]=f2b(v1.x); tmp[5]=f2b(v1.y); tmp[6]=f2b(v1.z); tmp[7]=f2b(v1.w);
      *(int4*)&Bl[n * 72 + kc * 8] = *(int4*)tmp;
    }
    __syncthreads();
    int r16 = lane & 15, khalf = lane >> 4;
    #pragma unroll
    for(int kk = 0; kk < 2; kk++){
      int ko = kk * 32 + khalf * 8;
      short8 bf = *(const short8*)&Bl[(wv * 16 + r16) * 72 + ko];
      #pragma unroll
      for(int mf = 0; mf < 9; mf++){
        short8 af = *(const short8*)&Al[(mf * 16 + r16) * 72 + ko];
        acc[mf] = __builtin_amdgcn_mfma_f32_16x16x32_bf16(af, bf, acc[mf], 0, 0, 0);
      }
    }
    __syncthreads();
  }
  int r16 = lane & 15, rgrp = lane >> 4;
  int n = n0 + wv * 16 + r16;
  #pragma unroll
  for(int mf = 0; mf < 9; mf++){
    #pragma unroll
    for(int r = 0; r < 4; r++){
      int m = mf * 16 + rgrp * 4 + r;
      part[((size_t)kz * 144 + m) * 4096 + n] = acc[mf][r];
    }
  }
}

// ------------- split-K reduce + bias + transpose into dw[b][n][9] -------------
__global__ __launch_bounds__(256) void k_red(const float* __restrict__ part,
    const float* __restrict__ kp_sb, float* __restrict__ dw){
  int i = blockIdx.x * 256 + threadIdx.x;   // 589824
  int m = i >> 12, n = i & 4095;
  float s = kp_sb[n];
  #pragma unroll
  for(int kz = 0; kz < 12; kz++) s += part[((size_t)kz * 144 + m) * 4096 + n];
  int q = m >> 4, b = m & 15;
  dw[((size_t)b * 4096 + n) * 9 + q] = s;
}

// ------ AdaConv fused (blocks 0..1023) + y1p pad-ring zero (blocks 1024..1551) ------
__global__ __launch_bounds__(256) void k_ada(const float* __restrict__ x,
    const float* __restrict__ dwb, const float* __restrict__ pwb,
    const float* __restrict__ biasb, unsigned short* __restrict__ y0p,
    unsigned short* __restrict__ y1p){
  int bg = blockIdx.x;
  if(bg >= 1024){
    int i = (bg - 1024) * 256 + threadIdx.x;   // 528*256 = 16*132*64
    int b = i / 8448, rem = i - b * 8448;
    int e = rem >> 6, ch8 = rem & 63;
    int hh, ww;
    if(e < 34){ hh = 0; ww = e; }
    else if(e < 68){ hh = 33; ww = e - 34; }
    else if(e < 100){ hh = e - 68 + 1; ww = 0; }
    else { hh = e - 100 + 1; ww = 33; }
    int4 z = {0, 0, 0, 0};
    *(int4*)&y1p[((size_t)(b * 34 + hh) * 34 + ww) * 512 + ch8 * 8] = z;
    return;
  }
  __shared__ float xn[8][1156];
  __shared__ float dwl[576];
  __shared__ float pwl[64];
  __shared__ float bl[8];
  __shared__ float red0[4][8], red1[4][8];
  __shared__ float ms[8], rs[8];
  int b = bg >> 6, g = bg & 63;
  int tid = threadIdx.x;
  int lane = tid & 63, wv = tid >> 6;
  for(int i = tid; i < 576; i += 256) dwl[i] = dwb[((size_t)b * 4096 + g * 64) * 9 + i];
  if(tid < 64) pwl[tid] = pwb[b * 4096 + g * 64 + tid];
  if(tid < 8)  bl[tid]  = biasb[b * 512 + g * 8 + tid];
  if(tid < 132){
    int e = tid, hh, ww;
    if(e < 34){ hh = 0; ww = e; }
    else if(e < 68){ hh = 33; ww = e - 34; }
    else if(e < 100){ hh = e - 68 + 1; ww = 0; }
    else { hh = e - 100 + 1; ww = 33; }
    int4 z = {0, 0, 0, 0};
    *(int4*)&y0p[((size_t)(b * 34 + hh) * 34 + ww) * 512 + g * 8] = z;
  }
  const float* xb = x + ((size_t)(b * 512 + g * 8)) * 1024;
  int h4 = tid >> 3, w4 = (tid & 7) * 4;
  float s[8], s2[8];
  #pragma unroll
  for(int ci = 0; ci < 8; ci++){
    float4 v = *(const float4*)(xb + ci * 1024 + tid * 4);
    float* dst = &xn[ci][(h4 + 1) * 34 + w4 + 1];
    dst[0] = v.x; dst[1] = v.y; dst[2] = v.z; dst[3] = v.w;
    s[ci]  = v.x + v.y + v.z + v.w;
    s2[ci] = v.x * v.x + v.y * v.y + v.z * v.z + v.w * v.w;
  }
  #pragma unroll
  for(int ci = 0; ci < 8; ci++){
    #pragma unroll
    for(int o = 32; o >= 1; o >>= 1){
      s[ci]  += __shfl_xor(s[ci],  o, 64);
      s2[ci] += __shfl_xor(s2[ci], o, 64);
    }
  }
  if(lane == 0){
    #pragma unroll
    for(int ci = 0; ci < 8; ci++){ red0[wv][ci] = s[ci]; red1[wv][ci] = s2[ci]; }
  }
  __syncthreads();
  if(tid < 8){
    float S  = red0[0][tid] + red0[1][tid] + red0[2][tid] + red0[3][tid];
    float S2 = red1[0][tid] + red1[1][tid] + red1[2][tid] + red1[3][tid];
    float m = S * (1.f / 1024.f);
    ms[tid] = m;
    rs[tid] = rsqrtf(S2 * (1.f / 1024.f) - m * m + 1e-5f);
  }
  __syncthreads();
  #pragma unroll
  for(int ci = 0; ci < 8; ci++){
    float m = ms[ci], r = rs[ci];
    float* p = &xn[ci][(h4 + 1) * 34 + w4 + 1];
    #pragma unroll
    for(int j = 0; j < 4; j++) p[j] = (p[j] - m) * r;
  }
  __syncthreads();
  for(int idx = tid; idx < 1056; idx += 256){
    int ci = idx / 132, e = idx - ci * 132;
    int hh, ww;
    if(e < 34){ hh = 0; ww = e; }
    else if(e < 68){ hh = 33; ww = e - 34; }
    else if(e < 100){ hh = e - 68 + 1; ww = 0; }
    else { hh = e - 100 + 1; ww = 33; }
    int h = hh - 1, w2 = ww - 1;
    h  = h  < 0 ? 1 : (h  > 31 ? 30 : h);
    w2 = w2 < 0 ? 1 : (w2 > 31 ? 30 : w2);
    xn[ci][hh * 34 + ww] = xn[ci][(h + 1) * 34 + (w2 + 1)];
  }
  __syncthreads();
  float acc[4][8] = {};
  #pragma unroll
  for(int i = 0; i < 8; i++){
    #pragma unroll
    for(int q = 0; q < 9; q++){
      int kh = q / 3, kw = q - kh * 3;
      float dvs[8];
      #pragma unroll
      for(int o = 0; o < 8; o++) dvs[o] = dwl[(o * 8 + i) * 9 + q];
      #pragma unroll
      for(int pp = 0; pp < 4; pp++){
        int p = pp * 256 + tid; int h = p >> 5, w = p & 31;
        float v = xn[i][(h + kh) * 34 + (w + kw)];
        #pragma unroll
        for(int o = 0; o < 8; o++) acc[pp][o] += v * dvs[o];
      }
    }
  }
  #pragma unroll
  for(int pp = 0; pp < 4; pp++){
    int p = pp * 256 + tid; int h = p >> 5, w = p & 31;
    unsigned short pack[8];
    #pragma unroll
    for(int o = 0; o < 8; o++){
      float sv = bl[o];
      #pragma unroll
      for(int i2 = 0; i2 < 8; i2++) sv += pwl[o * 8 + i2] * acc[pp][i2];
      pack[o] = f2b(sv);
    }
    *(int4*)&y0p[((size_t)(b * 34 + h + 1) * 34 + (w + 1)) * 512 + g * 8] = *(int4*)pack;
  }
}

// ------------- decoder conv, wave-pair split-K: BM=BN=128, 8 waves, pair (wv, wv+4) shares a 64x64 tile -------------
// khv = wv>>2 selects which K=32 half of each K-step the wave consumes -> 8 ds_read per 16 MFMA (0.5)
// while keeping 64 KB LDS (2 blocks/CU, 16 waves/CU). Counted-vmcnt two-barrier schedule (R4-proven).
// Epilogue: khv=1 waves dump acc to LDS (reuses tile buffers), khv=0 add + store.
// FUSE_UP=0: write padded NHWC bf16 (conv1). FUSE_UP=1: write d_out NCHW fp32 with 2x nearest upsample (conv2).
template<int FUSE_UP>
__global__ __launch_bounds__(512, 4) void k_convP(const unsigned short* __restrict__ inp,
    const unsigned short* __restrict__ wt, const float* __restrict__ bias,
    unsigned short* __restrict__ outp, float* __restrict__ outf){
  __shared__ __align__(16) char smraw[65536];
  unsigned short (*Al)[128 * 64] = (unsigned short(*)[128 * 64])smraw;
  unsigned short (*Bl)[128 * 64] = (unsigned short(*)[128 * 64])(smraw + 32768);
  float* red = (float*)smraw;
  int tid = threadIdx.x;
  int mt = blockIdx.x;                 // 128 m-tiles
  int n0 = blockIdx.y * 128;
  int b = mt >> 3, h0 = (mt & 7) * 4;
  int lane = tid & 63, wv = tid >> 6;
  int khv = wv >> 2, wsub = wv & 3;    // pair (wsub, khv): waves wsub and wsub+4 share tile
  int wm = (wsub >> 1) * 64, wn = (wsub & 1) * 64;
  f32x4 acc[4][4] = {};
  const size_t bbase = (size_t)b * 34 * 34 * 512;

  // staging: 4 gll16/thread (A 2 chunks + B 2 chunks); row = c>>3, slot = c&7, swizzled source
  int kc = tid & 7;
  int m0 = tid >> 3, m1 = (tid + 512) >> 3;
  int colA0 = kc ^ (m0 & 7), colA1 = kc ^ (m1 & 7);
  int mh0 = m0 >> 5, mw0 = m0 & 31;
  int mh1 = m1 >> 5, mw1 = m1 & 31;
  int ldsO0 = (tid & ~63) * 8;
  int ldsO1 = ldsO0 + 512 * 8;
  const unsigned short* a0base = inp + bbase + colA0 * 8;
  const unsigned short* a1base = inp + bbase + colA1 * 8;
  const unsigned short* b0base = wt + (size_t)(n0 + m0) * 4608 + colA0 * 8;
  const unsigned short* b1base = wt + (size_t)(n0 + m1) * 4608 + colA1 * 8;
  int r16 = lane & 15, khalf = lane >> 4;
  int sc8 = ((khv * 4 + khalf) ^ (r16 & 7)) * 8;   // loop-invariant swizzled read offset

#define STAGE(T, BUF) { \
    int q_ = (T) >> 3, cb_ = ((T) & 7) * 64; \
    int kh_ = q_ / 3, kw_ = q_ - kh_ * 3; \
    gll16(a0base + (size_t)((h0 + mh0 + kh_) * 34 + mw0 + kw_) * 512 + cb_, &Al[BUF][ldsO0]); \
    gll16(a1base + (size_t)((h0 + mh1 + kh_) * 34 + mw1 + kw_) * 512 + cb_, &Al[BUF][ldsO1]); \
    gll16(b0base + (size_t)q_ * 512 + cb_, &Bl[BUF][ldsO0]); \
    gll16(b1base + (size_t)q_ * 512 + cb_, &Bl[BUF][ldsO1]); }

#define COMPUTE(BUF) { \
    short8 af[4], bf[4]; \
    _Pragma("unroll") for(int i = 0; i < 4; i++) af[i] = *(const short8*)&Al[BUF][(wm + i * 16 + r16) * 64 + sc8]; \
    _Pragma("unroll") for(int i = 0; i < 4; i++) bf[i] = *(const short8*)&Bl[BUF][(wn + i * 16 + r16) * 64 + sc8]; \
    __builtin_amdgcn_s_setprio(1); \
    _Pragma("unroll") for(int mi = 0; mi < 4; mi++) \
      _Pragma("unroll") for(int ni = 0; ni < 4; ni++) \
        acc[mi][ni] = __builtin_amdgcn_mfma_f32_16x16x32_bf16(af[mi], bf[ni], acc[mi][ni], 0, 0, 0); \
    __builtin_amdgcn_s_setprio(0); }

  STAGE(0, 0)
  STAGE(1, 1)
  vm_wait4(); __builtin_amdgcn_s_barrier();
  for(int t = 0; t < 70; t += 2){
    COMPUTE(0)
    __builtin_amdgcn_s_barrier();
    STAGE(t + 2, 0)
    vm_wait4(); __builtin_amdgcn_s_barrier();
    COMPUTE(1)
    __builtin_amdgcn_s_barrier();
    STAGE(t + 3, 1)
    vm_wait4(); __builtin_amdgcn_s_barrier();
  }
  COMPUTE(0)
  vm_wait0(); __builtin_amdgcn_s_barrier();
  COMPUTE(1)
#undef STAGE
#undef COMPUTE

  // ---- pair reduction: khv=1 waves dump acc; khv=0 waves add ----
  __syncthreads();   // all waves done reading Al/Bl
  if(khv == 1){
    float* dst = red + wsub * 4096 + lane * 4;
    #pragma unroll
    for(int mi = 0; mi < 4; mi++)
      #pragma unroll
      for(int ni = 0; ni < 4; ni++)
        *(f32x4*)(dst + (mi * 4 + ni) * 256) = acc[mi][ni];
  }
  __syncthreads();
  if(khv == 0){
    const float* src = red + wsub * 4096 + lane * 4;
    #pragma unroll
    for(int mi = 0; mi < 4; mi++)
      #pragma unroll
      for(int ni = 0; ni < 4; ni++)
        acc[mi][ni] += *(const f32x4*)(src + (mi * 4 + ni) * 256);

    int rgrp = lane >> 4;
    #pragma unroll
    for(int ni = 0; ni < 4; ni++){
      int n = n0 + wn + ni * 16 + r16;
      float bv = bias[n];
      #pragma unroll
      for(int mi = 0; mi < 4; mi++){
        int row0 = wm + mi * 16 + rgrp * 4;
        int h = h0 + (row0 >> 5), w0 = row0 & 31;
        float v[4];
        #pragma unroll
        for(int r = 0; r < 4; r++){
          float t = acc[mi][ni][r] + bv;
          v[r] = t > 0.f ? t : 0.f;
        }
        if(FUSE_UP){
          // fused 2x nearest upsample -> NCHW fp32 [16][256][64][64]
          size_t base = ((size_t)(b * 256 + n) * 64 + 2 * h) * 64 + 2 * w0;
          float4 f0 = make_float4(v[0], v[0], v[1], v[1]);
          float4 f1 = make_float4(v[2], v[2], v[3], v[3]);
          *(float4*)&outf[base]          = f0;
          *(float4*)&outf[base + 4]      = f1;
          *(float4*)&outf[base + 64]     = f0;
          *(float4*)&outf[base + 64 + 4] = f1;
        } else {
          #pragma unroll
          for(int r = 0; r < 4; r++){
            int w = w0 + r;
            outp[((size_t)(b * 34 + h + 1) * 34 + (w + 1)) * 512 + n] = f2b(v[r]);
          }
        }
      }
    }
  }
}

extern "C" void kernel_launch(void* const* d_in, const int* in_sizes, int n_in,
                              void* d_out, int out_size, void* d_ws, size_t ws_size,
                              hipStream_t stream){
  (void)in_sizes; (void)n_in; (void)out_size; (void)ws_size;
  const float* x      = (const float*)d_in[0];
  const float* w      = (const float*)d_in[1];
  const float* kp_sw  = (const float*)d_in[2];
  const float* kp_sb  = (const float*)d_in[3];
  const float* kp_pw  = (const float*)d_in[4];
  const float* kp_pb  = (const float*)d_in[5];
  const float* kp_bw  = (const float*)d_in[6];
  const float* kp_bb  = (const float*)d_in[7];
  const float* dec_w1 = (const float*)d_in[8];
  const float* dec_b1 = (const float*)d_in[9];
  const float* dec_w2 = (const float*)d_in[10];
  const float* dec_b2 = (const float*)d_in[11];
  char* ws = (char*)d_ws;
  float*          pooled = (float*)(ws);                        // 32 KB
  float*          pw     = (float*)(ws + 32768);                // 256 KB
  float*          bias   = (float*)(ws + 294912);               // 32 KB
  unsigned short* Aim    = (unsigned short*)(ws + 393216);      // 1.33 MB
  float*          dw     = (float*)(ws + 1720320);              // 2.36 MB
  unsigned short* w1t    = (unsigned short*)(ws + 4079616);     // 4.72 MB
  unsigned short* w2t    = (unsigned short*)(ws + 8798208);     // 2.36 MB
  unsigned short* y0p    = (unsigned short*)(ws + 11157504);    // 18.94 MB
  unsigned short* y1p    = (unsigned short*)(ws + 30097408);    // 18.94 MB
  // split-K partials (12 x 144 x 4096 fp32 = 28.3 MB) alias y0p + y1p head;
  // consumed by k_red BEFORE k_ada (ring) / k_convP overwrite that region.
  float*          part   = (float*)(ws + 11157504);

  k_prepwt<<<944,  256, 0, stream>>>(w, Aim, pooled, dec_w1, dec_w2, w1t, w2t);
  k_pwgemm<<<1920, 256, 0, stream>>>(Aim, kp_sw, part, pooled,
                                     kp_pw, kp_pb, kp_bw, kp_bb, pw, bias);
  k_red   <<<2304, 256, 0, stream>>>(part, kp_sb, dw);
  k_ada   <<<1552, 256, 0, stream>>>(x, dw, pw, bias, y0p, y1p);
  k_convP<0><<<dim3(128, 4), 512, 0, stream>>>(y0p, w1t, dec_b1, y1p, nullptr);
  k_convP<1><<<dim3(128, 2), 512, 0, stream>>>(y1p, w2t, dec_b2, nullptr, (float*)d_out);
}

// Round 9
// 214.349 us; speedup vs baseline: 1.2681x; 1.0237x over previous
//
#include <hip/hip_runtime.h>

using short8 = __attribute__((ext_vector_type(8))) short;
using f32x4  = __attribute__((ext_vector_type(4))) float;

__device__ __forceinline__ unsigned short f2b(float f){
  unsigned int u = __float_as_uint(f);
  u = u + 0x7fffu + ((u >> 16) & 1u);   // round-to-nearest-even
  return (unsigned short)(u >> 16);
}
__device__ __forceinline__ float b2f(unsigned short s){
  return __uint_as_float(((unsigned int)s) << 16);
}

// async global->LDS, 16B per lane; lds ptr must be wave-uniform base
__device__ __forceinline__ void gll16(const void* g, void* l){
  __builtin_amdgcn_global_load_lds(
      (const __attribute__((address_space(1))) unsigned int*)g,
      (__attribute__((address_space(3))) unsigned int*)l, 16, 0, 0);
}
__device__ __forceinline__ void vm_wait4(){ asm volatile("s_waitcnt vmcnt(4)" ::: "memory"); }
__device__ __forceinline__ void vm_wait3(){ asm volatile("s_waitcnt vmcnt(3)" ::: "memory"); }
__device__ __forceinline__ void vm_wait0(){ asm volatile("s_waitcnt vmcnt(0)" ::: "memory"); }

// ------- fused: im2col (0..143) + pool (144..175) + decoder weight transform (176..943) -------
__global__ __launch_bounds__(256) void k_prepwt(const float* __restrict__ w,
    unsigned short* __restrict__ A, float* __restrict__ pooled,
    const float* __restrict__ w1, const float* __restrict__ w2,
    unsigned short* __restrict__ d1, unsigned short* __restrict__ d2){
  int bid = blockIdx.x;
  if(bid >= 176){
    __shared__ float ld[4608];
    int co = bid - 176;    // 768
    const float* src = (co < 512) ? (w1 + (size_t)co * 4608) : (w2 + (size_t)(co - 512) * 4608);
    unsigned short* dst = (co < 512) ? (d1 + (size_t)co * 4608) : (d2 + (size_t)(co - 512) * 4608);
    for(int i = threadIdx.x; i < 4608; i += 256) ld[i] = src[i];
    __syncthreads();
    for(int i = threadIdx.x; i < 4608; i += 256){
      int q = i >> 9, cin = i & 511;
      dst[i] = f2b(ld[cin * 9 + q]);
    }
    return;
  }
  if(bid >= 144){
    int i = (bid - 144) * 256 + threadIdx.x;   // 8192
    const float* p = w + (size_t)i * 9;
    float s = 0.f;
    #pragma unroll
    for(int j = 0; j < 9; j++) s += p[j];
    pooled[i] = s * (1.f / 9.f);
    return;
  }
  int row = bid;           // 144
  int pos = row >> 4, b = row & 15;
  int oh = pos / 3, ow = pos % 3;
  for(int k = threadIdx.x; k < 4608; k += 256){
    int cin = k / 9, q = k - cin * 9;
    int kh = q / 3, kw = q - kh * 3;
    int ih = oh + kh - 1, iw = ow + kw - 1;
    ih = ih < 0 ? -ih : (ih > 2 ? 4 - ih : ih);
    iw = iw < 0 ? -iw : (iw > 2 ? 4 - iw : iw);
    float v = w[((size_t)(b * 512 + cin) * 3 + ih) * 3 + iw];
    A[(size_t)row * 4608 + k] = f2b(v);
  }
}

// ------- merged: KernelPredictor spatial GEMM 8-way split-K (blocks 0..511) + pw/bias (512..1663) -------
__global__ __launch_bounds__(256) void k_pwgemm(const unsigned short* __restrict__ Aim,
    const float* __restrict__ kp_sw, float* __restrict__ part,
    const float* __restrict__ pooled,
    const float* __restrict__ kp_pw, const float* __restrict__ kp_pb,
    const float* __restrict__ kp_bw, const float* __restrict__ kp_bb,
    float* __restrict__ pw, float* __restrict__ bias){
  __shared__ unsigned short Al[144 * 72];
  __shared__ unsigned short Bl[64 * 72];
  int bid = blockIdx.x;
  int tid = threadIdx.x;
  int lane = tid & 63, wv = tid >> 6;
  if(bid >= 512){
    int wid = ((bid - 512) * 256 + tid) >> 6;   // 4608 waves
    const float* row;
    float bv;
    if(wid < 4096){ row = kp_pw + (size_t)wid * 512; bv = kp_pb[wid]; }
    else          { row = kp_bw + (size_t)(wid - 4096) * 512; bv = kp_bb[wid - 4096]; }
    float r[8];
    #pragma unroll
    for(int i = 0; i < 8; i++) r[i] = row[lane + 64 * i];
    for(int b = 0; b < 16; b++){
      float s = 0.f;
      #pragma unroll
      for(int i = 0; i < 8; i++) s += r[i] * pooled[b * 512 + lane + 64 * i];
      #pragma unroll
      for(int o = 32; o >= 1; o >>= 1) s += __shfl_xor(s, o, 64);
      if(lane == 0){
        if(wid < 4096) pw[b * 4096 + wid] = s + bv;
        else           bias[b * 512 + (wid - 4096)] = s + bv;
      }
    }
    return;
  }
  int n0 = (bid & 63) * 64;
  int kz = bid >> 6;                 // 0..7, 9 K-steps each
  f32x4 acc[9] = {};
  for(int ks = kz * 9; ks < kz * 9 + 9; ks++){
    int kb = ks * 64;
    for(int c = tid; c < 1152; c += 256){
      int m = c >> 3, kc = c & 7;
      *(int4*)&Al[m * 72 + kc * 8] = *(const int4*)(Aim + (size_t)m * 4608 + kb + kc * 8);
    }
    for(int c = tid; c < 512; c += 256){
      int n = c >> 3, kc = c & 7;
      const float4* src = (const float4*)(kp_sw + (size_t)(n0 + n) * 4608 + kb + kc * 8);
      float4 v0 = src[0], v1 = src[1];
      unsigned short tmp[8];
      tmp[0]=f2b(v0.x); tmp[1]=f2b(v0.y); tmp[2]=f2b(v0.z); tmp[3]=f2b(v0.w);
      tmp[4]=f2b(v1.x); tmp[5]=f2b(v1.y); tmp[6]=f2b(v1.z); tmp[7]=f2b(v1.w);
      *(int4*)&Bl[n * 72 + kc * 8] = *(int4*)tmp;
    }
    __syncthreads();
    int r16 = lane & 15, khalf = lane >> 4;
    #pragma unroll
    for(int kk = 0; kk < 2; kk++){
      int ko = kk * 32 + khalf * 8;
      short8 bf = *(const short8*)&Bl[(wv * 16 + r16) * 72 + ko];
      #pragma unroll
      for(int mf = 0; mf < 9; mf++){
        short8 af = *(const short8*)&Al[(mf * 16 + r16) * 72 + ko];
        acc[mf] = __builtin_amdgcn_mfma_f32_16x16x32_bf16(af, bf, acc[mf], 0, 0, 0);
      }
    }
    __syncthreads();
  }
  int r16 = lane & 15, rgrp = lane >> 4;
  int n = n0 + wv * 16 + r16;
  #pragma unroll
  for(int mf = 0; mf < 9; mf++){
    #pragma unroll
    for(int r = 0; r < 4; r++){
      int m = mf * 16 + rgrp * 4 + r;
      part[((size_t)kz * 144 + m) * 4096 + n] = acc[mf][r];
    }
  }
}

// ------ AdaConv fused: split-K reduce (dw in-block) + stats + IN + reflect-pad + conv + pointwise ------
__global__ __launch_bounds__(256) void k_ada(const float* __restrict__ x,
    const float* __restrict__ part, const float* __restrict__ kp_sb,
    const float* __restrict__ pwb, const float* __restrict__ biasb,
    unsigned short* __restrict__ y0p){
  __shared__ float xn[8][1156];
  __shared__ float dwl[576];
  __shared__ float pwl[64];
  __shared__ float bl[8];
  __shared__ float red0[4][8], red1[4][8];
  __shared__ float ms[8], rs[8];
  int bg = blockIdx.x;
  int b = bg >> 6, g = bg & 63;
  int tid = threadIdx.x;
  int lane = tid & 63, wv = tid >> 6;
  // dw reduce-in-block: dwl[nl*9+q] = kp_sb[n] + sum_kz part[kz][q*16+b][n]
  for(int i = tid; i < 576; i += 256){
    int q = i >> 6, nl = i & 63;
    float s = kp_sb[g * 64 + nl];
    #pragma unroll
    for(int kz = 0; kz < 8; kz++)
      s += part[((size_t)(kz * 144 + q * 16 + b)) * 4096 + g * 64 + nl];
    dwl[nl * 9 + q] = s;
  }
  if(tid < 64) pwl[tid] = pwb[b * 4096 + g * 64 + tid];
  if(tid < 8)  bl[tid]  = biasb[b * 512 + g * 8 + tid];
  // zero y0p pad ring for this (b,g) slice
  if(tid < 132){
    int e = tid, hh, ww;
    if(e < 34){ hh = 0; ww = e; }
    else if(e < 68){ hh = 33; ww = e - 34; }
    else if(e < 100){ hh = e - 68 + 1; ww = 0; }
    else { hh = e - 100 + 1; ww = 33; }
    int4 z = {0, 0, 0, 0};
    *(int4*)&y0p[((size_t)(b * 34 + hh) * 34 + ww) * 512 + g * 8] = z;
  }
  const float* xb = x + ((size_t)(b * 512 + g * 8)) * 1024;
  int h4 = tid >> 3, w4 = (tid & 7) * 4;
  float s[8], s2[8];
  #pragma unroll
  for(int ci = 0; ci < 8; ci++){
    float4 v = *(const float4*)(xb + ci * 1024 + tid * 4);
    float* dst = &xn[ci][(h4 + 1) * 34 + w4 + 1];
    dst[0] = v.x; dst[1] = v.y; dst[2] = v.z; dst[3] = v.w;
    s[ci]  = v.x + v.y + v.z + v.w;
    s2[ci] = v.x * v.x + v.y * v.y + v.z * v.z + v.w * v.w;
  }
  #pragma unroll
  for(int ci = 0; ci < 8; ci++){
    #pragma unroll
    for(int o = 32; o >= 1; o >>= 1){
      s[ci]  += __shfl_xor(s[ci],  o, 64);
      s2[ci] += __shfl_xor(s2[ci], o, 64);
    }
  }
  if(lane == 0){
    #pragma unroll
    for(int ci = 0; ci < 8; ci++){ red0[wv][ci] = s[ci]; red1[wv][ci] = s2[ci]; }
  }
  __syncthreads();
  if(tid < 8){
    float S  = red0[0][tid] + red0[1][tid] + red0[2][tid] + red0[3][tid];
    float S2 = red1[0][tid] + red1[1][tid] + red1[2][tid] + red1[3][tid];
    float m = S * (1.f / 1024.f);
    ms[tid] = m;
    rs[tid] = rsqrtf(S2 * (1.f / 1024.f) - m * m + 1e-5f);
  }
  __syncthreads();
  #pragma unroll
  for(int ci = 0; ci < 8; ci++){
    float m = ms[ci], r = rs[ci];
    float* p = &xn[ci][(h4 + 1) * 34 + w4 + 1];
    #pragma unroll
    for(int j = 0; j < 4; j++) p[j] = (p[j] - m) * r;
  }
  __syncthreads();
  for(int idx = tid; idx < 1056; idx += 256){
    int ci = idx / 132, e = idx - ci * 132;
    int hh, ww;
    if(e < 34){ hh = 0; ww = e; }
    else if(e < 68){ hh = 33; ww = e - 34; }
    else if(e < 100){ hh = e - 68 + 1; ww = 0; }
    else { hh = e - 100 + 1; ww = 33; }
    int h = hh - 1, w2 = ww - 1;
    h  = h  < 0 ? 1 : (h  > 31 ? 30 : h);
    w2 = w2 < 0 ? 1 : (w2 > 31 ? 30 : w2);
    xn[ci][hh * 34 + ww] = xn[ci][(h + 1) * 34 + (w2 + 1)];
  }
  __syncthreads();
  float acc[4][8] = {};
  #pragma unroll
  for(int i = 0; i < 8; i++){
    #pragma unroll
    for(int q = 0; q < 9; q++){
      int kh = q / 3, kw = q - kh * 3;
      float dvs[8];
      #pragma unroll
      for(int o = 0; o < 8; o++) dvs[o] = dwl[(o * 8 + i) * 9 + q];
      #pragma unroll
      for(int pp = 0; pp < 4; pp++){
        int p = pp * 256 + tid; int h = p >> 5, w = p & 31;
        float v = xn[i][(h + kh) * 34 + (w + kw)];
        #pragma unroll
        for(int o = 0; o < 8; o++) acc[pp][o] += v * dvs[o];
      }
    }
  }
  #pragma unroll
  for(int pp = 0; pp < 4; pp++){
    int p = pp * 256 + tid; int h = p >> 5, w = p & 31;
    unsigned short pack[8];
    #pragma unroll
    for(int o = 0; o < 8; o++){
      float sv = bl[o];
      #pragma unroll
      for(int i2 = 0; i2 < 8; i2++) sv += pwl[o * 8 + i2] * acc[pp][i2];
      pack[o] = f2b(sv);
    }
    *(int4*)&y0p[((size_t)(b * 34 + h + 1) * 34 + (w + 1)) * 512 + g * 8] = *(int4*)pack;
  }
}

// ------------- conv1 (R7-proven wave-pair split-K) + y1p pad-ring zero in y==4 blocks -------------
__global__ __launch_bounds__(512, 4) void k_conv1(const unsigned short* __restrict__ inp,
    const unsigned short* __restrict__ wt, const float* __restrict__ bias,
    unsigned short* __restrict__ outp){
  int tid = threadIdx.x;
  if(blockIdx.y == 4){
    // zero y1p pad ring (aliases split-K part buffer — dead after k_ada)
    for(int i = blockIdx.x * 512 + tid; i < 135168; i += 65536){
      int b = i / 8448, rem = i - b * 8448;
      int e = rem >> 6, ch8 = rem & 63;
      int hh, ww;
      if(e < 34){ hh = 0; ww = e; }
      else if(e < 68){ hh = 33; ww = e - 34; }
      else if(e < 100){ hh = e - 68 + 1; ww = 0; }
      else { hh = e - 100 + 1; ww = 33; }
      int4 z = {0, 0, 0, 0};
      *(int4*)&outp[((size_t)(b * 34 + hh) * 34 + ww) * 512 + ch8 * 8] = z;
    }
    return;
  }
  __shared__ __align__(16) char smraw[65536];
  unsigned short (*Al)[128 * 64] = (unsigned short(*)[128 * 64])smraw;
  unsigned short (*Bl)[128 * 64] = (unsigned short(*)[128 * 64])(smraw + 32768);
  float* red = (float*)smraw;
  int mt = blockIdx.x;
  int n0 = blockIdx.y * 128;
  int b = mt >> 3, h0 = (mt & 7) * 4;
  int lane = tid & 63, wv = tid >> 6;
  int khv = wv >> 2, wsub = wv & 3;
  int wm = (wsub >> 1) * 64, wn = (wsub & 1) * 64;
  f32x4 acc[4][4] = {};
  const size_t bbase = (size_t)b * 34 * 34 * 512;

  int kc = tid & 7;
  int m0 = tid >> 3, m1 = (tid + 512) >> 3;
  int colA0 = kc ^ (m0 & 7), colA1 = kc ^ (m1 & 7);
  int mh0 = m0 >> 5, mw0 = m0 & 31;
  int mh1 = m1 >> 5, mw1 = m1 & 31;
  int ldsO0 = (tid & ~63) * 8;
  int ldsO1 = ldsO0 + 512 * 8;
  const unsigned short* a0base = inp + bbase + colA0 * 8;
  const unsigned short* a1base = inp + bbase + colA1 * 8;
  const unsigned short* b0base = wt + (size_t)(n0 + m0) * 4608 + colA0 * 8;
  const unsigned short* b1base = wt + (size_t)(n0 + m1) * 4608 + colA1 * 8;
  int r16 = lane & 15, khalf = lane >> 4;
  int sc8 = ((khv * 4 + khalf) ^ (r16 & 7)) * 8;

#define STAGE(T, BUF) { \
    int q_ = (T) >> 3, cb_ = ((T) & 7) * 64; \
    int kh_ = q_ / 3, kw_ = q_ - kh_ * 3; \
    gll16(a0base + (size_t)((h0 + mh0 + kh_) * 34 + mw0 + kw_) * 512 + cb_, &Al[BUF][ldsO0]); \
    gll16(a1base + (size_t)((h0 + mh1 + kh_) * 34 + mw1 + kw_) * 512 + cb_, &Al[BUF][ldsO1]); \
    gll16(b0base + (size_t)q_ * 512 + cb_, &Bl[BUF][ldsO0]); \
    gll16(b1base + (size_t)q_ * 512 + cb_, &Bl[BUF][ldsO1]); }

#define COMPUTE(BUF) { \
    short8 af[4], bf[4]; \
    _Pragma("unroll") for(int i = 0; i < 4; i++) af[i] = *(const short8*)&Al[BUF][(wm + i * 16 + r16) * 64 + sc8]; \
    _Pragma("unroll") for(int i = 0; i < 4; i++) bf[i] = *(const short8*)&Bl[BUF][(wn + i * 16 + r16) * 64 + sc8]; \
    __builtin_amdgcn_s_setprio(1); \
    _Pragma("unroll") for(int mi = 0; mi < 4; mi++) \
      _Pragma("unroll") for(int ni = 0; ni < 4; ni++) \
        acc[mi][ni] = __builtin_amdgcn_mfma_f32_16x16x32_bf16(af[mi], bf[ni], acc[mi][ni], 0, 0, 0); \
    __builtin_amdgcn_s_setprio(0); }

  STAGE(0, 0)
  STAGE(1, 1)
  vm_wait4(); __builtin_amdgcn_s_barrier();
  for(int t = 0; t < 70; t += 2){
    COMPUTE(0)
    __builtin_amdgcn_s_barrier();
    STAGE(t + 2, 0)
    vm_wait4(); __builtin_amdgcn_s_barrier();
    COMPUTE(1)
    __builtin_amdgcn_s_barrier();
    STAGE(t + 3, 1)
    vm_wait4(); __builtin_amdgcn_s_barrier();
  }
  COMPUTE(0)
  vm_wait0(); __builtin_amdgcn_s_barrier();
  COMPUTE(1)
#undef STAGE
#undef COMPUTE

  __syncthreads();
  if(khv == 1){
    float* dst = red + wsub * 4096 + lane * 4;
    #pragma unroll
    for(int mi = 0; mi < 4; mi++)
      #pragma unroll
      for(int ni = 0; ni < 4; ni++)
        *(f32x4*)(dst + (mi * 4 + ni) * 256) = acc[mi][ni];
  }
  __syncthreads();
  if(khv == 0){
    const float* src = red + wsub * 4096 + lane * 4;
    #pragma unroll
    for(int mi = 0; mi < 4; mi++)
      #pragma unroll
      for(int ni = 0; ni < 4; ni++)
        acc[mi][ni] += *(const f32x4*)(src + (mi * 4 + ni) * 256);
    int rgrp = lane >> 4;
    #pragma unroll
    for(int ni = 0; ni < 4; ni++){
      int n = n0 + wn + ni * 16 + r16;
      float bv = bias[n];
      #pragma unroll
      for(int mi = 0; mi < 4; mi++){
        #pragma unroll
        for(int r = 0; r < 4; r++){
          int row = wm + mi * 16 + rgrp * 4 + r;
          int h = h0 + (row >> 5), w = row & 31;
          float v = acc[mi][ni][r] + bv;
          v = v > 0.f ? v : 0.f;
          outp[((size_t)(b * 34 + h + 1) * 34 + (w + 1)) * 512 + n] = f2b(v);
        }
      }
    }
  }
}

// ------------- conv2: BM=128 x BN=64, 48 KB LDS (2 blocks/CU), pair split-K, fused 2x upsample -------------
__global__ __launch_bounds__(512, 4) void k_conv2up(const unsigned short* __restrict__ inp,
    const unsigned short* __restrict__ wt, const float* __restrict__ bias,
    float* __restrict__ outf){
  __shared__ __align__(16) char smraw[49152];
  unsigned short (*Al)[128 * 64] = (unsigned short(*)[128 * 64])smraw;        // 2 x 16 KB
  unsigned short (*Bl)[64 * 64]  = (unsigned short(*)[64 * 64])(smraw + 32768); // 2 x 8 KB
  float* red = (float*)smraw;
  int tid = threadIdx.x;
  int mt = blockIdx.x;                 // 128 m-tiles
  int n0 = blockIdx.y * 64;            // 4 n-tiles
  int b = mt >> 3, h0 = (mt & 7) * 4;
  int lane = tid & 63, wv = tid >> 6;
  int khv = wv >> 2, wsub = wv & 3;
  int wm = (wsub >> 1) * 64, wn = (wsub & 1) * 32;
  f32x4 acc[4][2] = {};
  const size_t bbase = (size_t)b * 34 * 34 * 512;

  int kc = tid & 7;
  int m0 = tid >> 3, m1 = (tid + 512) >> 3;
  int colA0 = kc ^ (m0 & 7), colA1 = kc ^ (m1 & 7);
  int mh0 = m0 >> 5, mw0 = m0 & 31;
  int mh1 = m1 >> 5, mw1 = m1 & 31;
  int nB = tid >> 3;
  int cB = kc ^ (nB & 7);
  int ldsO0 = (tid & ~63) * 8;
  int ldsO1 = ldsO0 + 512 * 8;
  const unsigned short* a0base = inp + bbase + colA0 * 8;
  const unsigned short* a1base = inp + bbase + colA1 * 8;
  const unsigned short* bbse = wt + (size_t)(n0 + nB) * 4608 + cB * 8;
  int r16 = lane & 15, khalf = lane >> 4;
  int sc8 = ((khv * 4 + khalf) ^ (r16 & 7)) * 8;

#define STAGE(T, BUF) { \
    int q_ = (T) >> 3, cb_ = ((T) & 7) * 64; \
    int kh_ = q_ / 3, kw_ = q_ - kh_ * 3; \
    gll16(a0base + (size_t)((h0 + mh0 + kh_) * 34 + mw0 + kw_) * 512 + cb_, &Al[BUF][ldsO0]); \
    gll16(a1base + (size_t)((h0 + mh1 + kh_) * 34 + mw1 + kw_) * 512 + cb_, &Al[BUF][ldsO1]); \
    gll16(bbse + (size_t)q_ * 512 + cb_, &Bl[BUF][ldsO0]); }

#define COMPUTE(BUF) { \
    short8 af[4], bf[2]; \
    _Pragma("unroll") for(int i = 0; i < 4; i++) af[i] = *(const short8*)&Al[BUF][(wm + i * 16 + r16) * 64 + sc8]; \
    _Pragma("unroll") for(int i = 0; i < 2; i++) bf[i] = *(const short8*)&Bl[BUF][(wn + i * 16 + r16) * 64 + sc8]; \
    __builtin_amdgcn_s_setprio(1); \
    _Pragma("unroll") for(int mi = 0; mi < 4; mi++) \
      _Pragma("unroll") for(int ni = 0; ni < 2; ni++) \
        acc[mi][ni] = __builtin_amdgcn_mfma_f32_16x16x32_bf16(af[mi], bf[ni], acc[mi][ni], 0, 0, 0); \
    __builtin_amdgcn_s_setprio(0); }

  STAGE(0, 0)
  STAGE(1, 1)
  vm_wait3(); __builtin_amdgcn_s_barrier();
  for(int t = 0; t < 70; t += 2){
    COMPUTE(0)
    __builtin_amdgcn_s_barrier();
    STAGE(t + 2, 0)
    vm_wait3(); __builtin_amdgcn_s_barrier();
    COMPUTE(1)
    __builtin_amdgcn_s_barrier();
    STAGE(t + 3, 1)
    vm_wait3(); __builtin_amdgcn_s_barrier();
  }
  COMPUTE(0)
  vm_wait0(); __builtin_amdgcn_s_barrier();
  COMPUTE(1)
#undef STAGE
#undef COMPUTE

  __syncthreads();
  if(khv == 1){
    float* dst = red + wsub * 2048 + lane * 4;
    #pragma unroll
    for(int mi = 0; mi < 4; mi++)
      #pragma unroll
      for(int ni = 0; ni < 2; ni++)
        *(f32x4*)(dst + (mi * 2 + ni) * 256) = acc[mi][ni];
  }
  __syncthreads();
  if(khv == 0){
    const float* src = red + wsub * 2048 + lane * 4;
    #pragma unroll
    for(int mi = 0; mi < 4; mi++)
      #pragma unroll
      for(int ni = 0; ni < 2; ni++)
        acc[mi][ni] += *(const f32x4*)(src + (mi * 2 + ni) * 256);
    int rgrp = lane >> 4;
    #pragma unroll
    for(int ni = 0; ni < 2; ni++){
      int n = n0 + wn + ni * 16 + r16;
      float bv = bias[n];
      #pragma unroll
      for(int mi = 0; mi < 4; mi++){
        int row0 = wm + mi * 16 + rgrp * 4;
        int h = h0 + (row0 >> 5), w0 = row0 & 31;
        float v[4];
        #pragma unroll
        for(int r = 0; r < 4; r++){
          float t = acc[mi][ni][r] + bv;
          v[r] = t > 0.f ? t : 0.f;
        }
        size_t base = ((size_t)(b * 256 + n) * 64 + 2 * h) * 64 + 2 * w0;
        float4 f0 = make_float4(v[0], v[0], v[1], v[1]);
        float4 f1 = make_float4(v[2], v[2], v[3], v[3]);
        *(float4*)&outf[base]          = f0;
        *(float4*)&outf[base + 4]      = f1;
        *(float4*)&outf[base + 64]     = f0;
        *(float4*)&outf[base + 64 + 4] = f1;
      }
    }
  }
}

extern "C" void kernel_launch(void* const* d_in, const int* in_sizes, int n_in,
                              void* d_out, int out_size, void* d_ws, size_t ws_size,
                              hipStream_t stream){
  (void)in_sizes; (void)n_in; (void)out_size; (void)ws_size;
  const float* x      = (const float*)d_in[0];
  const float* w      = (const float*)d_in[1];
  const float* kp_sw  = (const float*)d_in[2];
  const float* kp_sb  = (const float*)d_in[3];
  const float* kp_pw  = (const float*)d_in[4];
  const float* kp_pb  = (const float*)d_in[5];
  const float* kp_bw  = (const float*)d_in[6];
  const float* kp_bb  = (const float*)d_in[7];
  const float* dec_w1 = (const float*)d_in[8];
  const float* dec_b1 = (const float*)d_in[9];
  const float* dec_w2 = (const float*)d_in[10];
  const float* dec_b2 = (const float*)d_in[11];
  char* ws = (char*)d_ws;
  float*          pooled = (float*)(ws);                        // 32 KB
  float*          pw     = (float*)(ws + 32768);                // 256 KB
  float*          bias   = (float*)(ws + 294912);               // 32 KB
  unsigned short* Aim    = (unsigned short*)(ws + 393216);      // 1.33 MB
  unsigned short* w1t    = (unsigned short*)(ws + 4079616);     // 4.72 MB
  unsigned short* w2t    = (unsigned short*)(ws + 8798208);     // 2.36 MB
  unsigned short* y0p    = (unsigned short*)(ws + 11157504);    // 18.94 MB
  unsigned short* y1p    = (unsigned short*)(ws + 30097408);    // 18.94 MB
  // split-K partials (8 x 144 x 4096 fp32 = 18.87 MB) alias y1p exactly;
  // read by k_ada, then y1p overwritten by k_conv1 (interior + ring blocks).
  float*          part   = (float*)(ws + 30097408);

  k_prepwt<<<944,  256, 0, stream>>>(w, Aim, pooled, dec_w1, dec_w2, w1t, w2t);
  k_pwgemm<<<1664, 256, 0, stream>>>(Aim, kp_sw, part, pooled,
                                     kp_pw, kp_pb, kp_bw, kp_bb, pw, bias);
  k_ada   <<<1024, 256, 0, stream>>>(x, part, kp_sb, pw, bias, y0p);
  k_conv1 <<<dim3(128, 5), 512, 0, stream>>>(y0p, w1t, dec_b1, y1p);
  k_conv2up<<<dim3(128, 4), 512, 0, stream>>>(y1p, w2t, dec_b2, (float*)d_out);
}